// Round 12
// baseline (11519.825 us; speedup 1.0000x reference)
//
#include <hip/hip_runtime.h>
#include <hip/hip_bf16.h>
#include <math.h>

typedef __attribute__((ext_vector_type(4))) float f32x4;

// ===========================================================================
// ROUND 12: OUTPUT DTYPE FIX. The harness doc: "d_out holds ... the
// reference's OUTPUT dtype (bfloat16 -> __hip_bfloat16*, else float*)".
// The reference returns float32 logits -> d_out is FLOAT32. Rounds 1-11
// wrote bf16 into an f32 buffer: f32 readback of interleaved bf16 pairs =
// same-scale decorrelated garbage + zero upper half => absmax ~ sqrt(2)*3.53
// = the exact signature observed in EVERY round (bit-identical across
// identical implementations, jittering 4.88-5.05 across layout variants).
// This is the only hypothesis explaining all 11 rounds with no other bug.
// Model: the exonerated naive pipeline (r4/r5), identity slots, C-order,
// int32 ids (proven by r1==r5), all scratch in ws (80 MiB, r1-proven).
// ===========================================================================

__global__ __launch_bounds__(256)
void embed_naive(const int* __restrict__ ids, const float* __restrict__ wte,
                 const float* __restrict__ wpe, float* __restrict__ h)
{
    int idx = blockIdx.x * 256 + threadIdx.x;    // 0 .. 2M-1
    int r = idx >> 10, d = idx & 1023;
    h[idx] = wte[(size_t)ids[r] * 1024 + d] + wpe[(size_t)(r & 1023) * 1024 + d];
}

__global__ __launch_bounds__(256)
void ln_naive(const float* __restrict__ x, const float* __restrict__ g,
              const float* __restrict__ b, float* __restrict__ out)
{
    __shared__ float partial[256];
    __shared__ float mv[2];
    int r = blockIdx.x, t = threadIdx.x;
    const float* xr = x + (size_t)r * 1024;
    float s = 0.f;
    for (int i = t; i < 1024; i += 256) s += xr[i];
    partial[t] = s; __syncthreads();
    if (t == 0) { float tot = 0.f; for (int i = 0; i < 256; ++i) tot += partial[i]; mv[0] = tot / 1024.f; }
    __syncthreads();
    float mean = mv[0];
    float s2 = 0.f;
    for (int i = t; i < 1024; i += 256) { float d = xr[i] - mean; s2 += d * d; }
    partial[t] = s2; __syncthreads();
    if (t == 0) { float tot = 0.f; for (int i = 0; i < 256; ++i) tot += partial[i]; mv[1] = rsqrtf(tot / 1024.f + 1e-5f); }
    __syncthreads();
    float rstd = mv[1];
    for (int i = t; i < 1024; i += 256)
        out[(size_t)r * 1024 + i] = (xr[i] - mean) * rstd * g[i] + b[i];
}

// Tiled f32 GEMM (exonerated). C = A@B (+bias)(+resid)(+GELU). f32 output.
template<bool GELU_ACT>
__global__ __launch_bounds__(256)
void gemm_f32(const float* __restrict__ A, const float* __restrict__ B,
              const float* __restrict__ bias, const float* __restrict__ resid,
              float* __restrict__ Cout, int M, int N, int K)
{
    __shared__ float As[16][72];
    __shared__ float Bs[16][72];
    const int t  = threadIdx.x;
    const int tx = t & 15;
    const int ty = t >> 4;
    const int m0 = blockIdx.x * 64;
    const int n0 = blockIdx.y * 64;

    float acc[4][4] = {};

    const int a_m  = t >> 2;
    const int a_k  = (t & 3) * 4;
    const int b_k  = t >> 4;
    const int b_n  = (t & 15) * 4;

    for (int k0 = 0; k0 < K; k0 += 16) {
        float4 fa = *(const float4*)(A + (size_t)(m0 + a_m) * K + k0 + a_k);
        As[a_k + 0][a_m] = fa.x;
        As[a_k + 1][a_m] = fa.y;
        As[a_k + 2][a_m] = fa.z;
        As[a_k + 3][a_m] = fa.w;
        float4 fb = *(const float4*)(B + (size_t)(k0 + b_k) * N + n0 + b_n);
        Bs[b_k][b_n + 0] = fb.x;
        Bs[b_k][b_n + 1] = fb.y;
        Bs[b_k][b_n + 2] = fb.z;
        Bs[b_k][b_n + 3] = fb.w;
        __syncthreads();
        #pragma unroll
        for (int kk = 0; kk < 16; ++kk) {
            f32x4 a4 = *(const f32x4*)&As[kk][ty * 4];
            f32x4 b4 = *(const f32x4*)&Bs[kk][tx * 4];
            #pragma unroll
            for (int i = 0; i < 4; ++i)
                #pragma unroll
                for (int j = 0; j < 4; ++j)
                    acc[i][j] += a4[i] * b4[j];
        }
        __syncthreads();
    }

    #pragma unroll
    for (int i = 0; i < 4; ++i) {
        int row = m0 + ty * 4 + i;
        #pragma unroll
        for (int j = 0; j < 4; ++j) {
            int col = n0 + tx * 4 + j;
            float v = acc[i][j] + (bias ? bias[col] : 0.f);
            if (resid) v += resid[(size_t)row * N + col];
            if (GELU_ACT) v = 0.5f * v * (1.f + erff(v * 0.70710678118654752f));
            Cout[(size_t)row * N + col] = v;
        }
    }
}

__global__ __launch_bounds__(64)
void attn_naive(const float* __restrict__ qkv, float* __restrict__ y)
{
    __shared__ float qv[64];
    __shared__ float sc[1024];
    int bid = blockIdx.x;            // b*16384 + h*1024 + q
    int q = bid & 1023;
    int h = (bid >> 10) & 15;
    int b = bid >> 14;
    int t = threadIdx.x;             // 0..63
    const float* base = qkv + (size_t)b * 1024 * 3072;
    qv[t] = base[(size_t)q * 3072 + h * 64 + t];
    __syncthreads();
    for (int k = t; k <= q; k += 64) {
        const float* kr = base + (size_t)k * 3072 + 1024 + h * 64;
        float s = 0.f;
        for (int d = 0; d < 64; ++d) s += qv[d] * kr[d];
        sc[k] = s * 0.125f;
    }
    __syncthreads();
    if (t == 0) {
        float m = -1e30f;
        for (int k = 0; k <= q; ++k) m = fmaxf(m, sc[k]);
        float sum = 0.f;
        for (int k = 0; k <= q; ++k) { float p = expf(sc[k] - m); sc[k] = p; sum += p; }
        float inv = 1.f / sum;
        for (int k = 0; k <= q; ++k) sc[k] *= inv;
    }
    __syncthreads();
    float o = 0.f;
    for (int k = 0; k <= q; ++k)
        o += sc[k] * base[(size_t)k * 3072 + 2048 + h * 64 + t];
    y[((size_t)(b * 1024 + q)) * 1024 + h * 64 + t] = o;
}

// ---------------------------------------------------------------------------
// Host launch. Scratch layout = round-1's exact 80 MiB ws footprint (proven
// safe by r1==r2 equivalence). d_out used ONLY for the final f32 logits.
// ---------------------------------------------------------------------------
extern "C" void kernel_launch(void* const* d_in, const int* in_sizes, int n_in,
                              void* d_out, int out_size, void* d_ws, size_t ws_size,
                              hipStream_t stream)
{
    (void)in_sizes; (void)n_in; (void)out_size; (void)ws_size;

    const int*   ids    = (const int*)d_in[0];    // int32 (proven: r1==r5)
    const float* wte    = (const float*)d_in[1];
    const float* wpe    = (const float*)d_in[2];
    const float* ln1_g  = (const float*)d_in[3];
    const float* ln1_b  = (const float*)d_in[4];
    const float* w_qkv  = (const float*)d_in[5];
    const float* b_qkv  = (const float*)d_in[6];
    const float* w_proj = (const float*)d_in[7];
    const float* b_proj = (const float*)d_in[8];
    const float* ln2_g  = (const float*)d_in[9];
    const float* ln2_b  = (const float*)d_in[10];
    const float* w_fc1  = (const float*)d_in[11];
    const float* b_fc1  = (const float*)d_in[12];
    const float* w_fc2  = (const float*)d_in[13];
    const float* b_fc2  = (const float*)d_in[14];
    const float* lnf_g  = (const float*)d_in[15];
    const float* lnf_b  = (const float*)d_in[16];
    const float* w_lm   = (const float*)d_in[17];

    float* hbuf = (float*)d_ws;        // 2048*1024
    float* abuf = hbuf + 2097152;      // 2048*1024
    float* qkvb = abuf + 2097152;      // 2048*3072
    float* ybuf = qkvb + 6291456;      // 2048*1024
    float* mbuf = ybuf + 2097152;      // 2048*4096  (total exactly 80 MiB)

    float* out  = (float*)d_out;       // f32 logits [2048][32000]

    embed_naive<<<8192, 256, 0, stream>>>(ids, wte, wpe, hbuf);

    for (int l = 0; l < 4; ++l) {
        ln_naive<<<2048, 256, 0, stream>>>(hbuf, ln1_g + l*1024, ln1_b + l*1024, abuf);
        gemm_f32<false><<<dim3(32, 48), 256, 0, stream>>>(
            abuf, w_qkv + (size_t)l*1024*3072, b_qkv + l*3072, nullptr, qkvb, 2048, 3072, 1024);
        attn_naive<<<32768, 64, 0, stream>>>(qkvb, ybuf);
        gemm_f32<false><<<dim3(32, 16), 256, 0, stream>>>(
            ybuf, w_proj + (size_t)l*1024*1024, b_proj + l*1024, hbuf, hbuf, 2048, 1024, 1024);
        ln_naive<<<2048, 256, 0, stream>>>(hbuf, ln2_g + l*1024, ln2_b + l*1024, abuf);
        gemm_f32<true><<<dim3(32, 64), 256, 0, stream>>>(
            abuf, w_fc1 + (size_t)l*1024*4096, b_fc1 + l*4096, nullptr, mbuf, 2048, 4096, 1024);
        gemm_f32<false><<<dim3(32, 16), 256, 0, stream>>>(
            mbuf, w_fc2 + (size_t)l*4096*1024, b_fc2 + l*1024, hbuf, hbuf, 2048, 1024, 4096);
    }

    ln_naive<<<2048, 256, 0, stream>>>(hbuf, lnf_g, lnf_b, abuf);
    gemm_f32<false><<<dim3(32, 500), 256, 0, stream>>>(
        abuf, w_lm, nullptr, nullptr, out, 2048, 32000, 1024);
}

// Round 13
// 2798.332 us; speedup vs baseline: 4.1167x; 4.1167x over previous
//
#include <hip/hip_runtime.h>
#include <hip/hip_bf16.h>
#include <math.h>

typedef __attribute__((ext_vector_type(4))) float f32x4;
typedef __attribute__((ext_vector_type(8))) short short8;

__device__ __forceinline__ unsigned short f2bf(float f) {
    return __builtin_bit_cast(unsigned short, __float2bfloat16(f));
}

// ---------------------------------------------------------------------------
// Embedding: h[b,t,:] = wte[ids[b,t],:] + wpe[t,:]
// ---------------------------------------------------------------------------
__global__ __launch_bounds__(256)
void embed_kernel(const int* __restrict__ ids, const float* __restrict__ wte,
                  const float* __restrict__ wpe, float* __restrict__ h)
{
    int row  = blockIdx.x;          // 0..2047 (b*T + t)
    int tpos = row & 1023;
    int id   = ids[row];
    float4 a = ((const float4*)(wte + (size_t)id * 1024))[threadIdx.x];
    float4 p = ((const float4*)(wpe + (size_t)tpos * 1024))[threadIdx.x];
    float4 o; o.x = a.x + p.x; o.y = a.y + p.y; o.z = a.z + p.z; o.w = a.w + p.w;
    ((float4*)(h + (size_t)row * 1024))[threadIdx.x] = o;
}

// ---------------------------------------------------------------------------
// LayerNorm (D=1024), one block of 256 per row, f32 in/out
// ---------------------------------------------------------------------------
__global__ __launch_bounds__(256)
void ln_kernel(const float* __restrict__ x, const float* __restrict__ g,
               const float* __restrict__ b, float* __restrict__ out)
{
    size_t row = blockIdx.x;
    float4 v = ((const float4*)(x + row * 1024))[threadIdx.x];
    float s  = v.x + v.y + v.z + v.w;
    float s2 = v.x*v.x + v.y*v.y + v.z*v.z + v.w*v.w;
    #pragma unroll
    for (int off = 32; off; off >>= 1) {
        s  += __shfl_xor(s, off);
        s2 += __shfl_xor(s2, off);
    }
    __shared__ float rs[4], rs2[4];
    int wave = threadIdx.x >> 6;
    if ((threadIdx.x & 63) == 0) { rs[wave] = s; rs2[wave] = s2; }
    __syncthreads();
    s  = rs[0] + rs[1] + rs[2] + rs[3];
    s2 = rs2[0] + rs2[1] + rs2[2] + rs2[3];
    float mean = s * (1.f / 1024.f);
    float var  = s2 * (1.f / 1024.f) - mean * mean;
    float rstd = rsqrtf(var + 1e-5f);
    float4 gg = ((const float4*)g)[threadIdx.x];
    float4 bb = ((const float4*)b)[threadIdx.x];
    float4 o;
    o.x = (v.x - mean) * rstd * gg.x + bb.x;
    o.y = (v.y - mean) * rstd * gg.y + bb.y;
    o.z = (v.z - mean) * rstd * gg.z + bb.z;
    o.w = (v.w - mean) * rstd * gg.w + bb.w;
    ((float4*)(out + row * 1024))[threadIdx.x] = o;
}

// ---------------------------------------------------------------------------
// GEMM: C[M,N] = A[M,K] @ B[K,N] (+bias) (+resid) (+GELU), bf16 MFMA, f32 acc,
// f32 output. A,B f32 in HBM, converted to bf16 while staging to LDS.
// Tile 128x128xK64, 4 waves, each wave 64x64 via 4x4 frags of 16x16x32.
// grid = (M/128, N/128). Validated: r1 MFMA output was bit-identical to the
// exonerated f32 GEMM (r4) under the same readback.
// ---------------------------------------------------------------------------
template<bool GELU_ACT>
__global__ __launch_bounds__(256)
void gemm_kernel(const float* __restrict__ A, const float* __restrict__ B,
                 const float* __restrict__ bias, const float* __restrict__ resid,
                 float* __restrict__ Cout, int M, int N, int K)
{
    __shared__ unsigned char smem[32768];   // A tile 16KB | B tile 16KB (bf16, swizzled)
    const int m0 = blockIdx.x * 128;
    const int n0 = blockIdx.y * 128;
    const int t    = threadIdx.x;
    const int lane = t & 63;
    const int wave = t >> 6;
    const int wm = (wave >> 1) * 64;
    const int wn = (wave & 1) * 64;

    f32x4 acc[4][4];
    #pragma unroll
    for (int i = 0; i < 4; ++i)
        #pragma unroll
        for (int j = 0; j < 4; ++j) {
            acc[i][j][0] = 0.f; acc[i][j][1] = 0.f; acc[i][j][2] = 0.f; acc[i][j][3] = 0.f;
        }

    const int a_row_base = t >> 3;        // 0..31
    const int a_k8       = (t & 7) * 8;   // 0..56
    const int b_n        = t & 127;       // 0..127
    const int b_k8base   = (t >> 7) * 8;  // 0 or 8

    for (int k0 = 0; k0 < K; k0 += 64) {
        // ---- stage A tile [128 rows][64 k] f32->bf16, XOR-swizzled ----
        #pragma unroll
        for (int pass = 0; pass < 4; ++pass) {
            int row = pass * 32 + a_row_base;
            const float* src = A + (size_t)(m0 + row) * K + k0 + a_k8;
            float4 f0 = *(const float4*)src;
            float4 f1 = *(const float4*)(src + 4);
            short8 w;
            w[0] = (short)f2bf(f0.x); w[1] = (short)f2bf(f0.y);
            w[2] = (short)f2bf(f0.z); w[3] = (short)f2bf(f0.w);
            w[4] = (short)f2bf(f1.x); w[5] = (short)f2bf(f1.y);
            w[6] = (short)f2bf(f1.z); w[7] = (short)f2bf(f1.w);
            int byte = row * 128 + ((a_k8 * 2) ^ ((row & 7) << 4));
            *(short8*)(smem + byte) = w;
        }
        // ---- stage B tile transposed: Bs[n][k] bf16, XOR-swizzled ----
        #pragma unroll
        for (int g = 0; g < 4; ++g) {
            int k8 = b_k8base + g * 16;
            const float* src = B + (size_t)(k0 + k8) * N + n0 + b_n;
            short8 w;
            #pragma unroll
            for (int j = 0; j < 8; ++j) w[j] = (short)f2bf(src[(size_t)j * N]);
            int byte = 16384 + b_n * 128 + ((k8 * 2) ^ ((b_n & 7) << 4));
            *(short8*)(smem + byte) = w;
        }
        __syncthreads();
        // ---- compute ----
        const int lr = lane & 15;
        const int lk = lane >> 4;
        #pragma unroll
        for (int ks = 0; ks < 2; ++ks) {
            int chunk = ks * 4 + lk;      // 0..7 (16B chunk index along k)
            short8 af[4], bfr[4];
            #pragma unroll
            for (int m = 0; m < 4; ++m) {
                int row = wm + m * 16 + lr;
                af[m] = *(const short8*)(smem + row * 128 + ((chunk * 16) ^ ((row & 7) << 4)));
            }
            #pragma unroll
            for (int n = 0; n < 4; ++n) {
                int nn = wn + n * 16 + lr;
                bfr[n] = *(const short8*)(smem + 16384 + nn * 128 + ((chunk * 16) ^ ((nn & 7) << 4)));
            }
            #pragma unroll
            for (int m = 0; m < 4; ++m)
                #pragma unroll
                for (int n = 0; n < 4; ++n)
                    acc[m][n] = __builtin_amdgcn_mfma_f32_16x16x32_bf16(af[m], bfr[n], acc[m][n], 0, 0, 0);
        }
        __syncthreads();
    }

    // ---- epilogue (C/D layout: col=lane&15, row=(lane>>4)*4+j) ----
    const int lr = lane & 15;
    const int lq = lane >> 4;
    #pragma unroll
    for (int n = 0; n < 4; ++n) {
        int col = n0 + wn + n * 16 + lr;
        float bv = bias ? bias[col] : 0.f;
        #pragma unroll
        for (int m = 0; m < 4; ++m) {
            int rbase = m0 + wm + m * 16 + lq * 4;
            #pragma unroll
            for (int j = 0; j < 4; ++j) {
                int row = rbase + j;
                float v = acc[m][n][j] + bv;
                if (resid) v += resid[(size_t)row * N + col];
                if (GELU_ACT) v = 0.5f * v * (1.f + erff(v * 0.70710678118654752f));
                Cout[(size_t)row * N + col] = v;
            }
        }
    }
}

// ---------------------------------------------------------------------------
// Causal attention, f32. qkv layout [B,T,3*D]; head dim 64, H=16, T=1024.
// One block = 4 waves = 4 consecutive q rows of one (b,h). Online softmax,
// wave-parallel scores (lane j = key j) and accumulation (lane d = dim d).
// grid = B*H*(T/4) = 8192 blocks.
// ---------------------------------------------------------------------------
__global__ __launch_bounds__(256)
void attn_kernel(const float* __restrict__ qkv, float* __restrict__ y)
{
    __shared__ float Kt[64][65];
    __shared__ float Vt[64][65];
    __shared__ float Qs[4][64];
    __shared__ float Ps[4][64];

    const int qi   = blockIdx.x & 255;   // q-group within (b,h)
    const int bh   = blockIdx.x >> 8;    // 0..31
    const int b    = bh >> 4;
    const int h    = bh & 15;
    const int wave = threadIdx.x >> 6;
    const int lane = threadIdx.x & 63;
    const int q    = qi * 4 + wave;

    const size_t base_b = (size_t)b * 1024 * 3072;

    Qs[wave][lane] = qkv[base_b + (size_t)q * 3072 + h * 64 + lane] * 0.125f;

    float o = 0.f, mrun = -INFINITY, lrun = 0.f;
    const int ntiles = (qi * 4 + 3) / 64 + 1;

    const int srow = threadIdx.x >> 2;        // 0..63
    const int sd   = (threadIdx.x & 3) * 16;  // 0,16,32,48

    for (int tile = 0; tile < ntiles; ++tile) {
        __syncthreads();
        const int kb = tile * 64;
        const float* kbase = qkv + base_b + (size_t)(kb + srow) * 3072 + 1024 + h * 64 + sd;
        const float* vbase = kbase + 1024;
        #pragma unroll
        for (int p = 0; p < 4; ++p) {
            float4 kv = *(const float4*)(kbase + p * 4);
            float4 vv = *(const float4*)(vbase + p * 4);
            Kt[srow][sd + p*4 + 0] = kv.x; Kt[srow][sd + p*4 + 1] = kv.y;
            Kt[srow][sd + p*4 + 2] = kv.z; Kt[srow][sd + p*4 + 3] = kv.w;
            Vt[srow][sd + p*4 + 0] = vv.x; Vt[srow][sd + p*4 + 1] = vv.y;
            Vt[srow][sd + p*4 + 2] = vv.z; Vt[srow][sd + p*4 + 3] = vv.w;
        }
        __syncthreads();

        // scores: lane j computes s_j = q . K[j]
        int kidx = kb + lane;
        float s = -INFINITY;
        if (kidx <= q) {
            float a = 0.f;
            #pragma unroll 8
            for (int d = 0; d < 64; ++d) a += Qs[wave][d] * Kt[lane][d];
            s = a;
        }
        float tm = s;
        #pragma unroll
        for (int off = 32; off; off >>= 1) tm = fmaxf(tm, __shfl_xor(tm, off));
        float mnew = fmaxf(mrun, tm);
        float sc = expf(mrun - mnew);     // 0 on first tile (mrun=-inf, mnew finite)
        float p  = expf(s - mnew);        // 0 for masked lanes
        Ps[wave][lane] = p;
        float ps = p;
        #pragma unroll
        for (int off = 32; off; off >>= 1) ps += __shfl_xor(ps, off);
        lrun = lrun * sc + ps;
        mrun = mnew;
        o *= sc;
        __syncthreads();
        // accumulate: lane d
        #pragma unroll 8
        for (int j = 0; j < 64; ++j) o += Ps[wave][j] * Vt[j][lane];
    }

    y[(size_t)(b * 1024 + q) * 1024 + h * 64 + lane] = o / lrun;
}

// ---------------------------------------------------------------------------
// Host launch. d_out = f32 logits (proven r12). Scratch: 80 MiB in d_ws.
// ---------------------------------------------------------------------------
extern "C" void kernel_launch(void* const* d_in, const int* in_sizes, int n_in,
                              void* d_out, int out_size, void* d_ws, size_t ws_size,
                              hipStream_t stream)
{
    (void)in_sizes; (void)n_in; (void)out_size; (void)ws_size;

    const int*   ids    = (const int*)d_in[0];
    const float* wte    = (const float*)d_in[1];
    const float* wpe    = (const float*)d_in[2];
    const float* ln1_g  = (const float*)d_in[3];
    const float* ln1_b  = (const float*)d_in[4];
    const float* w_qkv  = (const float*)d_in[5];
    const float* b_qkv  = (const float*)d_in[6];
    const float* w_proj = (const float*)d_in[7];
    const float* b_proj = (const float*)d_in[8];
    const float* ln2_g  = (const float*)d_in[9];
    const float* ln2_b  = (const float*)d_in[10];
    const float* w_fc1  = (const float*)d_in[11];
    const float* b_fc1  = (const float*)d_in[12];
    const float* w_fc2  = (const float*)d_in[13];
    const float* b_fc2  = (const float*)d_in[14];
    const float* lnf_g  = (const float*)d_in[15];
    const float* lnf_b  = (const float*)d_in[16];
    const float* w_lm   = (const float*)d_in[17];

    float* hbuf = (float*)d_ws;        // 2048*1024
    float* abuf = hbuf + 2097152;      // 2048*1024
    float* qkvb = abuf + 2097152;      // 2048*3072
    float* ybuf = qkvb + 6291456;      // 2048*1024
    float* mbuf = ybuf + 2097152;      // 2048*4096  (total 80 MiB)

    float* out  = (float*)d_out;       // f32 logits [2048][32000]

    embed_kernel<<<2048, 256, 0, stream>>>(ids, wte, wpe, hbuf);

    for (int l = 0; l < 4; ++l) {
        ln_kernel<<<2048, 256, 0, stream>>>(hbuf, ln1_g + l*1024, ln1_b + l*1024, abuf);
        gemm_kernel<false><<<dim3(16, 24), 256, 0, stream>>>(
            abuf, w_qkv + (size_t)l*1024*3072, b_qkv + l*3072, nullptr, qkvb, 2048, 3072, 1024);
        attn_kernel<<<8192, 256, 0, stream>>>(qkvb, ybuf);
        gemm_kernel<false><<<dim3(16, 8), 256, 0, stream>>>(
            ybuf, w_proj + (size_t)l*1024*1024, b_proj + l*1024, hbuf, hbuf, 2048, 1024, 1024);
        ln_kernel<<<2048, 256, 0, stream>>>(hbuf, ln2_g + l*1024, ln2_b + l*1024, abuf);
        gemm_kernel<true><<<dim3(16, 32), 256, 0, stream>>>(
            abuf, w_fc1 + (size_t)l*1024*4096, b_fc1 + l*4096, nullptr, mbuf, 2048, 4096, 1024);
        gemm_kernel<false><<<dim3(16, 8), 256, 0, stream>>>(
            mbuf, w_fc2 + (size_t)l*4096*1024, b_fc2 + l*1024, hbuf, hbuf, 2048, 1024, 4096);
    }

    ln_kernel<<<2048, 256, 0, stream>>>(hbuf, lnf_g, lnf_b, abuf);
    gemm_kernel<false><<<dim3(16, 250), 256, 0, stream>>>(
        abuf, w_lm, nullptr, nullptr, out, 2048, 32000, 1024);
}

// Round 14
// 2653.593 us; speedup vs baseline: 4.3412x; 1.0545x over previous
//
#include <hip/hip_runtime.h>
#include <hip/hip_bf16.h>
#include <math.h>

typedef __attribute__((ext_vector_type(4))) float f32x4;
typedef __attribute__((ext_vector_type(8))) short short8;

__device__ __forceinline__ unsigned short f2bf(float f) {
    return __builtin_bit_cast(unsigned short, __float2bfloat16(f));
}

// ---------------------------------------------------------------------------
// Embedding: h[b,t,:] = wte[ids[b,t],:] + wpe[t,:]
// ---------------------------------------------------------------------------
__global__ __launch_bounds__(256)
void embed_kernel(const int* __restrict__ ids, const float* __restrict__ wte,
                  const float* __restrict__ wpe, float* __restrict__ h)
{
    int row  = blockIdx.x;          // 0..2047 (b*T + t)
    int tpos = row & 1023;
    int id   = ids[row];
    float4 a = ((const float4*)(wte + (size_t)id * 1024))[threadIdx.x];
    float4 p = ((const float4*)(wpe + (size_t)tpos * 1024))[threadIdx.x];
    float4 o; o.x = a.x + p.x; o.y = a.y + p.y; o.z = a.z + p.z; o.w = a.w + p.w;
    ((float4*)(h + (size_t)row * 1024))[threadIdx.x] = o;
}

// ---------------------------------------------------------------------------
// LayerNorm (D=1024), one block of 256 per row, f32 in/out
// ---------------------------------------------------------------------------
__global__ __launch_bounds__(256)
void ln_kernel(const float* __restrict__ x, const float* __restrict__ g,
               const float* __restrict__ b, float* __restrict__ out)
{
    size_t row = blockIdx.x;
    float4 v = ((const float4*)(x + row * 1024))[threadIdx.x];
    float s  = v.x + v.y + v.z + v.w;
    float s2 = v.x*v.x + v.y*v.y + v.z*v.z + v.w*v.w;
    #pragma unroll
    for (int off = 32; off; off >>= 1) {
        s  += __shfl_xor(s, off);
        s2 += __shfl_xor(s2, off);
    }
    __shared__ float rs[4], rs2[4];
    int wave = threadIdx.x >> 6;
    if ((threadIdx.x & 63) == 0) { rs[wave] = s; rs2[wave] = s2; }
    __syncthreads();
    s  = rs[0] + rs[1] + rs[2] + rs[3];
    s2 = rs2[0] + rs2[1] + rs2[2] + rs2[3];
    float mean = s * (1.f / 1024.f);
    float var  = s2 * (1.f / 1024.f) - mean * mean;
    float rstd = rsqrtf(var + 1e-5f);
    float4 gg = ((const float4*)g)[threadIdx.x];
    float4 bb = ((const float4*)b)[threadIdx.x];
    float4 o;
    o.x = (v.x - mean) * rstd * gg.x + bb.x;
    o.y = (v.y - mean) * rstd * gg.y + bb.y;
    o.z = (v.z - mean) * rstd * gg.z + bb.z;
    o.w = (v.w - mean) * rstd * gg.w + bb.w;
    ((float4*)(out + row * 1024))[threadIdx.x] = o;
}

// ---------------------------------------------------------------------------
// GEMM: bf16 MFMA, f32 acc, f32 out. 128x128xK64 tile, 4 waves. (r13, proven)
// ---------------------------------------------------------------------------
template<bool GELU_ACT>
__global__ __launch_bounds__(256)
void gemm_kernel(const float* __restrict__ A, const float* __restrict__ B,
                 const float* __restrict__ bias, const float* __restrict__ resid,
                 float* __restrict__ Cout, int M, int N, int K)
{
    __shared__ unsigned char smem[32768];
    const int m0 = blockIdx.x * 128;
    const int n0 = blockIdx.y * 128;
    const int t    = threadIdx.x;
    const int lane = t & 63;
    const int wave = t >> 6;
    const int wm = (wave >> 1) * 64;
    const int wn = (wave & 1) * 64;

    f32x4 acc[4][4];
    #pragma unroll
    for (int i = 0; i < 4; ++i)
        #pragma unroll
        for (int j = 0; j < 4; ++j) {
            acc[i][j][0] = 0.f; acc[i][j][1] = 0.f; acc[i][j][2] = 0.f; acc[i][j][3] = 0.f;
        }

    const int a_row_base = t >> 3;
    const int a_k8       = (t & 7) * 8;
    const int b_n        = t & 127;
    const int b_k8base   = (t >> 7) * 8;

    for (int k0 = 0; k0 < K; k0 += 64) {
        #pragma unroll
        for (int pass = 0; pass < 4; ++pass) {
            int row = pass * 32 + a_row_base;
            const float* src = A + (size_t)(m0 + row) * K + k0 + a_k8;
            float4 f0 = *(const float4*)src;
            float4 f1 = *(const float4*)(src + 4);
            short8 w;
            w[0] = (short)f2bf(f0.x); w[1] = (short)f2bf(f0.y);
            w[2] = (short)f2bf(f0.z); w[3] = (short)f2bf(f0.w);
            w[4] = (short)f2bf(f1.x); w[5] = (short)f2bf(f1.y);
            w[6] = (short)f2bf(f1.z); w[7] = (short)f2bf(f1.w);
            int byte = row * 128 + ((a_k8 * 2) ^ ((row & 7) << 4));
            *(short8*)(smem + byte) = w;
        }
        #pragma unroll
        for (int g = 0; g < 4; ++g) {
            int k8 = b_k8base + g * 16;
            const float* src = B + (size_t)(k0 + k8) * N + n0 + b_n;
            short8 w;
            #pragma unroll
            for (int j = 0; j < 8; ++j) w[j] = (short)f2bf(src[(size_t)j * N]);
            int byte = 16384 + b_n * 128 + ((k8 * 2) ^ ((b_n & 7) << 4));
            *(short8*)(smem + byte) = w;
        }
        __syncthreads();
        const int lr = lane & 15;
        const int lk = lane >> 4;
        #pragma unroll
        for (int ks = 0; ks < 2; ++ks) {
            int chunk = ks * 4 + lk;
            short8 af[4], bfr[4];
            #pragma unroll
            for (int m = 0; m < 4; ++m) {
                int row = wm + m * 16 + lr;
                af[m] = *(const short8*)(smem + row * 128 + ((chunk * 16) ^ ((row & 7) << 4)));
            }
            #pragma unroll
            for (int n = 0; n < 4; ++n) {
                int nn = wn + n * 16 + lr;
                bfr[n] = *(const short8*)(smem + 16384 + nn * 128 + ((chunk * 16) ^ ((nn & 7) << 4)));
            }
            #pragma unroll
            for (int m = 0; m < 4; ++m)
                #pragma unroll
                for (int n = 0; n < 4; ++n)
                    acc[m][n] = __builtin_amdgcn_mfma_f32_16x16x32_bf16(af[m], bfr[n], acc[m][n], 0, 0, 0);
        }
        __syncthreads();
    }

    const int lr = lane & 15;
    const int lq = lane >> 4;
    #pragma unroll
    for (int n = 0; n < 4; ++n) {
        int col = n0 + wn + n * 16 + lr;
        float bv = bias ? bias[col] : 0.f;
        #pragma unroll
        for (int m = 0; m < 4; ++m) {
            int rbase = m0 + wm + m * 16 + lq * 4;
            #pragma unroll
            for (int j = 0; j < 4; ++j) {
                int row = rbase + j;
                float v = acc[m][n][j] + bv;
                if (resid) v += resid[(size_t)row * N + col];
                if (GELU_ACT) v = 0.5f * v * (1.f + erff(v * 0.70710678118654752f));
                Cout[(size_t)row * N + col] = v;
            }
        }
    }
}

// ---------------------------------------------------------------------------
// Causal attention v2, f32. One block = 4 waves x 4 q-rows = 16 rows of one
// (b,h). grid = B*H*(T/16) = 2048 blocks, (b,h)-major.
// K stored TRANSPOSED in LDS (Kt[d][key]) so the score phase reads are
// lane-contiguous scalars reused across 4 rows (4 independent FMA chains).
// V stored [key][d] so PV reads Vt[j][lane] lane-contiguous, reused 4x.
// Q/P read as aligned float4 broadcasts (conflict-free).
// ---------------------------------------------------------------------------
__global__ __launch_bounds__(256)
void attn_kernel(const float* __restrict__ qkv, float* __restrict__ y)
{
    __shared__ float Kt[64][65];   // [d][key]
    __shared__ float Vt[64][65];   // [key][d]
    __shared__ float Qs[16][64];   // [row][d]   (float4-aligned rows)
    __shared__ float Ps[16][64];   // [row][key]

    const int qg   = blockIdx.x & 63;    // q-group (16 rows) within (b,h)
    const int bh   = blockIdx.x >> 6;    // 0..31
    const int b    = bh >> 4;
    const int h    = bh & 15;
    const int wave = threadIdx.x >> 6;
    const int lane = threadIdx.x & 63;
    const int r0   = wave * 4;           // block-local first row of this wave
    const int qbase = qg * 16;

    const size_t base_b = (size_t)b * 1024 * 3072;

    #pragma unroll
    for (int i = 0; i < 4; ++i)
        Qs[r0 + i][lane] =
            qkv[base_b + (size_t)(qbase + r0 + i) * 3072 + h * 64 + lane] * 0.125f;

    float o[4]    = {0.f, 0.f, 0.f, 0.f};
    float mrun[4] = {-INFINITY, -INFINITY, -INFINITY, -INFINITY};
    float lrun[4] = {0.f, 0.f, 0.f, 0.f};

    const int ntiles = (qbase + 15) / 64 + 1;
    const int srow = threadIdx.x >> 2;        // 0..63
    const int sd   = (threadIdx.x & 3) * 16;  // 0,16,32,48

    for (int tile = 0; tile < ntiles; ++tile) {
        __syncthreads();
        const int kb = tile * 64;
        const float* kbase = qkv + base_b + (size_t)(kb + srow) * 3072 + 1024 + h * 64 + sd;
        const float* vbase = kbase + 1024;
        #pragma unroll
        for (int p = 0; p < 4; ++p) {
            float4 kv = *(const float4*)(kbase + p * 4);
            float4 vv = *(const float4*)(vbase + p * 4);
            Kt[sd + p*4 + 0][srow] = kv.x; Kt[sd + p*4 + 1][srow] = kv.y;
            Kt[sd + p*4 + 2][srow] = kv.z; Kt[sd + p*4 + 3][srow] = kv.w;
            Vt[srow][sd + p*4 + 0] = vv.x; Vt[srow][sd + p*4 + 1] = vv.y;
            Vt[srow][sd + p*4 + 2] = vv.z; Vt[srow][sd + p*4 + 3] = vv.w;
        }
        __syncthreads();

        // ---- scores: lane = key j; 4 rows in parallel ----
        float s0 = 0.f, s1 = 0.f, s2 = 0.f, s3 = 0.f;
        #pragma unroll
        for (int d0 = 0; d0 < 64; d0 += 4) {
            float k0 = Kt[d0 + 0][lane];
            float k1 = Kt[d0 + 1][lane];
            float k2 = Kt[d0 + 2][lane];
            float k3 = Kt[d0 + 3][lane];
            float4 q0 = *(const float4*)&Qs[r0 + 0][d0];
            float4 q1 = *(const float4*)&Qs[r0 + 1][d0];
            float4 q2 = *(const float4*)&Qs[r0 + 2][d0];
            float4 q3 = *(const float4*)&Qs[r0 + 3][d0];
            s0 += q0.x*k0 + q0.y*k1 + q0.z*k2 + q0.w*k3;
            s1 += q1.x*k0 + q1.y*k1 + q1.z*k2 + q1.w*k3;
            s2 += q2.x*k0 + q2.y*k1 + q2.z*k2 + q2.w*k3;
            s3 += q3.x*k0 + q3.y*k1 + q3.z*k2 + q3.w*k3;
        }
        float sv[4] = {s0, s1, s2, s3};
        const int kidx = kb + lane;
        #pragma unroll
        for (int r = 0; r < 4; ++r) {
            int q = qbase + r0 + r;
            float sr = (kidx <= q) ? sv[r] : -INFINITY;
            float tm = sr;
            #pragma unroll
            for (int off = 32; off; off >>= 1) tm = fmaxf(tm, __shfl_xor(tm, off));
            float mnew = fmaxf(mrun[r], tm);      // finite from tile 0 onward
            float sc = expf(mrun[r] - mnew);      // 0 on first tile
            float p  = expf(sr - mnew);           // 0 for masked lanes
            Ps[r0 + r][lane] = p;
            float ps = p;
            #pragma unroll
            for (int off = 32; off; off >>= 1) ps += __shfl_xor(ps, off);
            lrun[r] = lrun[r] * sc + ps;
            mrun[r] = mnew;
            o[r] *= sc;
        }
        __syncthreads();

        // ---- PV: lane = dim d; 4 rows in parallel, V reused 4x ----
        #pragma unroll
        for (int j0 = 0; j0 < 64; j0 += 4) {
            float v0 = Vt[j0 + 0][lane];
            float v1 = Vt[j0 + 1][lane];
            float v2 = Vt[j0 + 2][lane];
            float v3 = Vt[j0 + 3][lane];
            #pragma unroll
            for (int r = 0; r < 4; ++r) {
                float4 pf = *(const float4*)&Ps[r0 + r][j0];
                o[r] += pf.x*v0 + pf.y*v1 + pf.z*v2 + pf.w*v3;
            }
        }
    }

    #pragma unroll
    for (int r = 0; r < 4; ++r)
        y[(size_t)(b * 1024 + qbase + r0 + r) * 1024 + h * 64 + lane] = o[r] / lrun[r];
}

// ---------------------------------------------------------------------------
// Host launch. d_out = f32 logits. Scratch: 80 MiB in d_ws.
// ---------------------------------------------------------------------------
extern "C" void kernel_launch(void* const* d_in, const int* in_sizes, int n_in,
                              void* d_out, int out_size, void* d_ws, size_t ws_size,
                              hipStream_t stream)
{
    (void)in_sizes; (void)n_in; (void)out_size; (void)ws_size;

    const int*   ids    = (const int*)d_in[0];
    const float* wte    = (const float*)d_in[1];
    const float* wpe    = (const float*)d_in[2];
    const float* ln1_g  = (const float*)d_in[3];
    const float* ln1_b  = (const float*)d_in[4];
    const float* w_qkv  = (const float*)d_in[5];
    const float* b_qkv  = (const float*)d_in[6];
    const float* w_proj = (const float*)d_in[7];
    const float* b_proj = (const float*)d_in[8];
    const float* ln2_g  = (const float*)d_in[9];
    const float* ln2_b  = (const float*)d_in[10];
    const float* w_fc1  = (const float*)d_in[11];
    const float* b_fc1  = (const float*)d_in[12];
    const float* w_fc2  = (const float*)d_in[13];
    const float* b_fc2  = (const float*)d_in[14];
    const float* lnf_g  = (const float*)d_in[15];
    const float* lnf_b  = (const float*)d_in[16];
    const float* w_lm   = (const float*)d_in[17];

    float* hbuf = (float*)d_ws;        // 2048*1024
    float* abuf = hbuf + 2097152;      // 2048*1024
    float* qkvb = abuf + 2097152;      // 2048*3072
    float* ybuf = qkvb + 6291456;      // 2048*1024
    float* mbuf = ybuf + 2097152;      // 2048*4096  (total 80 MiB)

    float* out  = (float*)d_out;       // f32 logits [2048][32000]

    embed_kernel<<<2048, 256, 0, stream>>>(ids, wte, wpe, hbuf);

    for (int l = 0; l < 4; ++l) {
        ln_kernel<<<2048, 256, 0, stream>>>(hbuf, ln1_g + l*1024, ln1_b + l*1024, abuf);
        gemm_kernel<false><<<dim3(16, 24), 256, 0, stream>>>(
            abuf, w_qkv + (size_t)l*1024*3072, b_qkv + l*3072, nullptr, qkvb, 2048, 3072, 1024);
        attn_kernel<<<2048, 256, 0, stream>>>(qkvb, ybuf);
        gemm_kernel<false><<<dim3(16, 8), 256, 0, stream>>>(
            ybuf, w_proj + (size_t)l*1024*1024, b_proj + l*1024, hbuf, hbuf, 2048, 1024, 1024);
        ln_kernel<<<2048, 256, 0, stream>>>(hbuf, ln2_g + l*1024, ln2_b + l*1024, abuf);
        gemm_kernel<true><<<dim3(16, 32), 256, 0, stream>>>(
            abuf, w_fc1 + (size_t)l*1024*4096, b_fc1 + l*4096, nullptr, mbuf, 2048, 4096, 1024);
        gemm_kernel<false><<<dim3(16, 8), 256, 0, stream>>>(
            mbuf, w_fc2 + (size_t)l*4096*1024, b_fc2 + l*1024, hbuf, hbuf, 2048, 1024, 4096);
    }

    ln_kernel<<<2048, 256, 0, stream>>>(hbuf, lnf_g, lnf_b, abuf);
    gemm_kernel<false><<<dim3(16, 250), 256, 0, stream>>>(
        abuf, w_lm, nullptr, nullptr, out, 2048, 32000, 1024);
}

// Round 15
// 2503.072 us; speedup vs baseline: 4.6023x; 1.0601x over previous
//
#include <hip/hip_runtime.h>
#include <hip/hip_bf16.h>
#include <math.h>

typedef __attribute__((ext_vector_type(4))) float f32x4;
typedef __attribute__((ext_vector_type(8))) short short8;

__device__ __forceinline__ unsigned short f2bf(float f) {
    return __builtin_bit_cast(unsigned short, __float2bfloat16(f));
}

// ---------------------------------------------------------------------------
// Embedding: h[b,t,:] = wte[ids[b,t],:] + wpe[t,:]
// ---------------------------------------------------------------------------
__global__ __launch_bounds__(256)
void embed_kernel(const int* __restrict__ ids, const float* __restrict__ wte,
                  const float* __restrict__ wpe, float* __restrict__ h)
{
    int row  = blockIdx.x;          // 0..2047 (b*T + t)
    int tpos = row & 1023;
    int id   = ids[row];
    float4 a = ((const float4*)(wte + (size_t)id * 1024))[threadIdx.x];
    float4 p = ((const float4*)(wpe + (size_t)tpos * 1024))[threadIdx.x];
    float4 o; o.x = a.x + p.x; o.y = a.y + p.y; o.z = a.z + p.z; o.w = a.w + p.w;
    ((float4*)(h + (size_t)row * 1024))[threadIdx.x] = o;
}

// ---------------------------------------------------------------------------
// LayerNorm (D=1024), one block of 256 per row, f32 in/out
// ---------------------------------------------------------------------------
__global__ __launch_bounds__(256)
void ln_kernel(const float* __restrict__ x, const float* __restrict__ g,
               const float* __restrict__ b, float* __restrict__ out)
{
    size_t row = blockIdx.x;
    float4 v = ((const float4*)(x + row * 1024))[threadIdx.x];
    float s  = v.x + v.y + v.z + v.w;
    float s2 = v.x*v.x + v.y*v.y + v.z*v.z + v.w*v.w;
    #pragma unroll
    for (int off = 32; off; off >>= 1) {
        s  += __shfl_xor(s, off);
        s2 += __shfl_xor(s2, off);
    }
    __shared__ float rs[4], rs2[4];
    int wave = threadIdx.x >> 6;
    if ((threadIdx.x & 63) == 0) { rs[wave] = s; rs2[wave] = s2; }
    __syncthreads();
    s  = rs[0] + rs[1] + rs[2] + rs[3];
    s2 = rs2[0] + rs2[1] + rs2[2] + rs2[3];
    float mean = s * (1.f / 1024.f);
    float var  = s2 * (1.f / 1024.f) - mean * mean;
    float rstd = rsqrtf(var + 1e-5f);
    float4 gg = ((const float4*)g)[threadIdx.x];
    float4 bb = ((const float4*)b)[threadIdx.x];
    float4 o;
    o.x = (v.x - mean) * rstd * gg.x + bb.x;
    o.y = (v.y - mean) * rstd * gg.y + bb.y;
    o.z = (v.z - mean) * rstd * gg.z + bb.z;
    o.w = (v.w - mean) * rstd * gg.w + bb.w;
    ((float4*)(out + row * 1024))[threadIdx.x] = o;
}

// ---------------------------------------------------------------------------
// GEMM: bf16 MFMA, f32 acc, f32 out. 128x128xK64 tile, 4 waves.
// 1-D grid with XCD-chunked bijective swizzle (n-major within each XCD) so
// blocks sharing a B column-panel land on the same XCD's L2.
// nwg must be a multiple of 8 and M a multiple of 128*? (GM = M/128 = 16).
// ---------------------------------------------------------------------------
template<bool GELU_ACT>
__global__ __launch_bounds__(256)
void gemm_kernel(const float* __restrict__ A, const float* __restrict__ B,
                 const float* __restrict__ bias, const float* __restrict__ resid,
                 float* __restrict__ Cout, int M, int N, int K)
{
    __shared__ unsigned char smem[32768];
    // --- XCD-chunked swizzle (bijective since gridDim.x % 8 == 0) ---
    const int per   = gridDim.x >> 3;
    const int newid = (blockIdx.x & 7) * per + (blockIdx.x >> 3);
    const int m0 = (newid & 15) * 128;   // GM = 16 (M = 2048)
    const int n0 = (newid >> 4) * 128;

    const int t    = threadIdx.x;
    const int lane = t & 63;
    const int wave = t >> 6;
    const int wm = (wave >> 1) * 64;
    const int wn = (wave & 1) * 64;

    f32x4 acc[4][4];
    #pragma unroll
    for (int i = 0; i < 4; ++i)
        #pragma unroll
        for (int j = 0; j < 4; ++j) {
            acc[i][j][0] = 0.f; acc[i][j][1] = 0.f; acc[i][j][2] = 0.f; acc[i][j][3] = 0.f;
        }

    const int a_row_base = t >> 3;
    const int a_k8       = (t & 7) * 8;
    const int b_n        = t & 127;
    const int b_k8base   = (t >> 7) * 8;

    for (int k0 = 0; k0 < K; k0 += 64) {
        #pragma unroll
        for (int pass = 0; pass < 4; ++pass) {
            int row = pass * 32 + a_row_base;
            const float* src = A + (size_t)(m0 + row) * K + k0 + a_k8;
            float4 f0 = *(const float4*)src;
            float4 f1 = *(const float4*)(src + 4);
            short8 w;
            w[0] = (short)f2bf(f0.x); w[1] = (short)f2bf(f0.y);
            w[2] = (short)f2bf(f0.z); w[3] = (short)f2bf(f0.w);
            w[4] = (short)f2bf(f1.x); w[5] = (short)f2bf(f1.y);
            w[6] = (short)f2bf(f1.z); w[7] = (short)f2bf(f1.w);
            int byte = row * 128 + ((a_k8 * 2) ^ ((row & 7) << 4));
            *(short8*)(smem + byte) = w;
        }
        #pragma unroll
        for (int g = 0; g < 4; ++g) {
            int k8 = b_k8base + g * 16;
            const float* src = B + (size_t)(k0 + k8) * N + n0 + b_n;
            short8 w;
            #pragma unroll
            for (int j = 0; j < 8; ++j) w[j] = (short)f2bf(src[(size_t)j * N]);
            int byte = 16384 + b_n * 128 + ((k8 * 2) ^ ((b_n & 7) << 4));
            *(short8*)(smem + byte) = w;
        }
        __syncthreads();
        const int lr = lane & 15;
        const int lk = lane >> 4;
        #pragma unroll
        for (int ks = 0; ks < 2; ++ks) {
            int chunk = ks * 4 + lk;
            short8 af[4], bfr[4];
            #pragma unroll
            for (int m = 0; m < 4; ++m) {
                int row = wm + m * 16 + lr;
                af[m] = *(const short8*)(smem + row * 128 + ((chunk * 16) ^ ((row & 7) << 4)));
            }
            #pragma unroll
            for (int n = 0; n < 4; ++n) {
                int nn = wn + n * 16 + lr;
                bfr[n] = *(const short8*)(smem + 16384 + nn * 128 + ((chunk * 16) ^ ((nn & 7) << 4)));
            }
            #pragma unroll
            for (int m = 0; m < 4; ++m)
                #pragma unroll
                for (int n = 0; n < 4; ++n)
                    acc[m][n] = __builtin_amdgcn_mfma_f32_16x16x32_bf16(af[m], bfr[n], acc[m][n], 0, 0, 0);
        }
        __syncthreads();
    }

    const int lr = lane & 15;
    const int lq = lane >> 4;
    #pragma unroll
    for (int n = 0; n < 4; ++n) {
        int col = n0 + wn + n * 16 + lr;
        float bv = bias ? bias[col] : 0.f;
        #pragma unroll
        for (int m = 0; m < 4; ++m) {
            int rbase = m0 + wm + m * 16 + lq * 4;
            #pragma unroll
            for (int j = 0; j < 4; ++j) {
                int row = rbase + j;
                float v = acc[m][n][j] + bv;
                if (resid) v += resid[(size_t)row * N + col];
                if (GELU_ACT) v = 0.5f * v * (1.f + erff(v * 0.70710678118654752f));
                Cout[(size_t)row * N + col] = v;
            }
        }
    }
}

// ---------------------------------------------------------------------------
// Causal attention v3, f32. One block = 4 waves x 4 q-rows = 16 rows of one
// (b,h). grid = 2048 blocks.
// Key change vs v2: NO per-tile cross-lane reductions. Softmax is computed
// WITHOUT max subtraction (shift-invariant; |s| <~ 6 with LN'd inputs so
// exp is far from overflow), and the denominator is accumulated per-lane
// (lane j owns keys kb+j) and reduced ONCE at the end. This removes the
// serial 6-deep shfl chains (2 per row per tile) that bounded v1/v2.
// ---------------------------------------------------------------------------
__global__ __launch_bounds__(256)
void attn_kernel(const float* __restrict__ qkv, float* __restrict__ y)
{
    __shared__ float Kt[64][65];   // [d][key]
    __shared__ float Vt[64][65];   // [key][d]
    __shared__ float Qs[16][64];   // [row][d]
    __shared__ float Ps[16][64];   // [row][key]

    const int qg   = blockIdx.x & 63;    // q-group (16 rows) within (b,h)
    const int bh   = blockIdx.x >> 6;    // 0..31
    const int b    = bh >> 4;
    const int h    = bh & 15;
    const int wave = threadIdx.x >> 6;
    const int lane = threadIdx.x & 63;
    const int r0   = wave * 4;
    const int qbase = qg * 16;

    const size_t base_b = (size_t)b * 1024 * 3072;

    #pragma unroll
    for (int i = 0; i < 4; ++i)
        Qs[r0 + i][lane] =
            qkv[base_b + (size_t)(qbase + r0 + i) * 3072 + h * 64 + lane] * 0.125f;

    float o[4]    = {0.f, 0.f, 0.f, 0.f};
    float lsum[4] = {0.f, 0.f, 0.f, 0.f};

    const int ntiles = (qbase + 15) / 64 + 1;
    const int srow = threadIdx.x >> 2;        // 0..63
    const int sd   = (threadIdx.x & 3) * 16;  // 0,16,32,48

    for (int tile = 0; tile < ntiles; ++tile) {
        __syncthreads();
        const int kb = tile * 64;
        const float* kbase = qkv + base_b + (size_t)(kb + srow) * 3072 + 1024 + h * 64 + sd;
        const float* vbase = kbase + 1024;
        #pragma unroll
        for (int p = 0; p < 4; ++p) {
            float4 kv = *(const float4*)(kbase + p * 4);
            float4 vv = *(const float4*)(vbase + p * 4);
            Kt[sd + p*4 + 0][srow] = kv.x; Kt[sd + p*4 + 1][srow] = kv.y;
            Kt[sd + p*4 + 2][srow] = kv.z; Kt[sd + p*4 + 3][srow] = kv.w;
            Vt[srow][sd + p*4 + 0] = vv.x; Vt[srow][sd + p*4 + 1] = vv.y;
            Vt[srow][sd + p*4 + 2] = vv.z; Vt[srow][sd + p*4 + 3] = vv.w;
        }
        __syncthreads();

        // ---- scores: lane = key j; 4 rows in parallel ----
        float s0 = 0.f, s1 = 0.f, s2 = 0.f, s3 = 0.f;
        #pragma unroll
        for (int d0 = 0; d0 < 64; d0 += 4) {
            float k0 = Kt[d0 + 0][lane];
            float k1 = Kt[d0 + 1][lane];
            float k2 = Kt[d0 + 2][lane];
            float k3 = Kt[d0 + 3][lane];
            float4 q0 = *(const float4*)&Qs[r0 + 0][d0];
            float4 q1 = *(const float4*)&Qs[r0 + 1][d0];
            float4 q2 = *(const float4*)&Qs[r0 + 2][d0];
            float4 q3 = *(const float4*)&Qs[r0 + 3][d0];
            s0 += q0.x*k0 + q0.y*k1 + q0.z*k2 + q0.w*k3;
            s1 += q1.x*k0 + q1.y*k1 + q1.z*k2 + q1.w*k3;
            s2 += q2.x*k0 + q2.y*k1 + q2.z*k2 + q2.w*k3;
            s3 += q3.x*k0 + q3.y*k1 + q3.z*k2 + q3.w*k3;
        }
        float sv[4] = {s0, s1, s2, s3};
        const int kidx = kb + lane;
        #pragma unroll
        for (int r = 0; r < 4; ++r) {
            int q = qbase + r0 + r;
            float p = (kidx <= q) ? __expf(sv[r]) : 0.f;   // softmax w/o shift
            Ps[r0 + r][lane] = p;
            lsum[r] += p;                                   // deferred denom
        }
        // Ps written and read by the SAME wave -> wave-lockstep, no barrier.

        // ---- PV: lane = dim d; 4 rows in parallel, V reused 4x ----
        #pragma unroll
        for (int j0 = 0; j0 < 64; j0 += 4) {
            float v0 = Vt[j0 + 0][lane];
            float v1 = Vt[j0 + 1][lane];
            float v2 = Vt[j0 + 2][lane];
            float v3 = Vt[j0 + 3][lane];
            #pragma unroll
            for (int r = 0; r < 4; ++r) {
                float4 pf = *(const float4*)&Ps[r0 + r][j0];
                o[r] += pf.x*v0 + pf.y*v1 + pf.z*v2 + pf.w*v3;
            }
        }
    }

    // ---- final: one reduction per row, then normalize ----
    #pragma unroll
    for (int r = 0; r < 4; ++r) {
        float l = lsum[r];
        #pragma unroll
        for (int off = 32; off; off >>= 1) l += __shfl_xor(l, off);
        y[(size_t)(b * 1024 + qbase + r0 + r) * 1024 + h * 64 + lane] = o[r] / l;
    }
}

// ---------------------------------------------------------------------------
// Host launch. d_out = f32 logits. Scratch: 80 MiB in d_ws.
// GEMM grids are 1-D (nwg = GM*GN, multiple of 8 for the XCD swizzle).
// ---------------------------------------------------------------------------
extern "C" void kernel_launch(void* const* d_in, const int* in_sizes, int n_in,
                              void* d_out, int out_size, void* d_ws, size_t ws_size,
                              hipStream_t stream)
{
    (void)in_sizes; (void)n_in; (void)out_size; (void)ws_size;

    const int*   ids    = (const int*)d_in[0];
    const float* wte    = (const float*)d_in[1];
    const float* wpe    = (const float*)d_in[2];
    const float* ln1_g  = (const float*)d_in[3];
    const float* ln1_b  = (const float*)d_in[4];
    const float* w_qkv  = (const float*)d_in[5];
    const float* b_qkv  = (const float*)d_in[6];
    const float* w_proj = (const float*)d_in[7];
    const float* b_proj = (const float*)d_in[8];
    const float* ln2_g  = (const float*)d_in[9];
    const float* ln2_b  = (const float*)d_in[10];
    const float* w_fc1  = (const float*)d_in[11];
    const float* b_fc1  = (const float*)d_in[12];
    const float* w_fc2  = (const float*)d_in[13];
    const float* b_fc2  = (const float*)d_in[14];
    const float* lnf_g  = (const float*)d_in[15];
    const float* lnf_b  = (const float*)d_in[16];
    const float* w_lm   = (const float*)d_in[17];

    float* hbuf = (float*)d_ws;        // 2048*1024
    float* abuf = hbuf + 2097152;      // 2048*1024
    float* qkvb = abuf + 2097152;      // 2048*3072
    float* ybuf = qkvb + 6291456;      // 2048*1024
    float* mbuf = ybuf + 2097152;      // 2048*4096  (total 80 MiB)

    float* out  = (float*)d_out;       // f32 logits [2048][32000]

    embed_kernel<<<2048, 256, 0, stream>>>(ids, wte, wpe, hbuf);

    for (int l = 0; l < 4; ++l) {
        ln_kernel<<<2048, 256, 0, stream>>>(hbuf, ln1_g + l*1024, ln1_b + l*1024, abuf);
        gemm_kernel<false><<<16*24, 256, 0, stream>>>(
            abuf, w_qkv + (size_t)l*1024*3072, b_qkv + l*3072, nullptr, qkvb, 2048, 3072, 1024);
        attn_kernel<<<2048, 256, 0, stream>>>(qkvb, ybuf);
        gemm_kernel<false><<<16*8, 256, 0, stream>>>(
            ybuf, w_proj + (size_t)l*1024*1024, b_proj + l*1024, hbuf, hbuf, 2048, 1024, 1024);
        ln_kernel<<<2048, 256, 0, stream>>>(hbuf, ln2_g + l*1024, ln2_b + l*1024, abuf);
        gemm_kernel<true><<<16*32, 256, 0, stream>>>(
            abuf, w_fc1 + (size_t)l*1024*4096, b_fc1 + l*4096, nullptr, mbuf, 2048, 4096, 1024);
        gemm_kernel<false><<<16*8, 256, 0, stream>>>(
            mbuf, w_fc2 + (size_t)l*4096*1024, b_fc2 + l*1024, hbuf, hbuf, 2048, 1024, 4096);
    }

    ln_kernel<<<2048, 256, 0, stream>>>(hbuf, lnf_g, lnf_b, abuf);
    gemm_kernel<false><<<16*250, 256, 0, stream>>>(
        abuf, w_lm, nullptr, nullptr, out, 2048, 32000, 1024);
}

// Round 16
// 2084.545 us; speedup vs baseline: 5.5263x; 1.2008x over previous
//
#include <hip/hip_runtime.h>
#include <hip/hip_bf16.h>
#include <math.h>

typedef __attribute__((ext_vector_type(4))) float f32x4;
typedef __attribute__((ext_vector_type(8))) short short8;
typedef __attribute__((ext_vector_type(4))) unsigned short ushort4v;

__device__ __forceinline__ unsigned short f2bf(float f) {
    return __builtin_bit_cast(unsigned short, __float2bfloat16(f));
}

// ---------------------------------------------------------------------------
// Transpose-cast: in f32 [K][N] (layer z) -> out bf16 [N][K] (k-contiguous)
// ---------------------------------------------------------------------------
__global__ __launch_bounds__(256)
void tc_kernel(const float* __restrict__ in, __hip_bfloat16* __restrict__ out,
               int N, int K)
{
    __shared__ float tile[64][65];
    const size_t loff = (size_t)blockIdx.z * K * N;
    const int k0 = blockIdx.x * 64, n0 = blockIdx.y * 64;
    const int t = threadIdx.x;
    {
        int kk = t >> 2, nb = (t & 3) * 16;
        const float* src = in + loff + (size_t)(k0 + kk) * N + n0 + nb;
        #pragma unroll
        for (int j = 0; j < 4; ++j) {
            float4 v = *(const float4*)(src + j * 4);
            tile[kk][nb + j*4 + 0] = v.x; tile[kk][nb + j*4 + 1] = v.y;
            tile[kk][nb + j*4 + 2] = v.z; tile[kk][nb + j*4 + 3] = v.w;
        }
    }
    __syncthreads();
    {
        int nn = t >> 2, kb = (t & 3) * 16;
        __hip_bfloat16* dst = out + loff + (size_t)(n0 + nn) * K + k0 + kb;
        short8 w0, w1;
        #pragma unroll
        for (int j = 0; j < 8; ++j) w0[j] = (short)f2bf(tile[kb + j][nn]);
        #pragma unroll
        for (int j = 0; j < 8; ++j) w1[j] = (short)f2bf(tile[kb + 8 + j][nn]);
        *(short8*)dst = w0;
        *(short8*)(dst + 8) = w1;
    }
}

// ---------------------------------------------------------------------------
// Embedding: h[b,t,:] = wte[ids[b,t],:] + wpe[t,:]  (f32 out)
// ---------------------------------------------------------------------------
__global__ __launch_bounds__(256)
void embed_kernel(const int* __restrict__ ids, const float* __restrict__ wte,
                  const float* __restrict__ wpe, float* __restrict__ h)
{
    int row  = blockIdx.x;
    int tpos = row & 1023;
    int id   = ids[row];
    float4 a = ((const float4*)(wte + (size_t)id * 1024))[threadIdx.x];
    float4 p = ((const float4*)(wpe + (size_t)tpos * 1024))[threadIdx.x];
    float4 o; o.x = a.x + p.x; o.y = a.y + p.y; o.z = a.z + p.z; o.w = a.w + p.w;
    ((float4*)(h + (size_t)row * 1024))[threadIdx.x] = o;
}

// ---------------------------------------------------------------------------
// LayerNorm (D=1024), f32 in, BF16 out (feeds GEMM A only)
// ---------------------------------------------------------------------------
__global__ __launch_bounds__(256)
void ln_kernel(const float* __restrict__ x, const float* __restrict__ g,
               const float* __restrict__ b, __hip_bfloat16* __restrict__ out)
{
    size_t row = blockIdx.x;
    float4 v = ((const float4*)(x + row * 1024))[threadIdx.x];
    float s  = v.x + v.y + v.z + v.w;
    float s2 = v.x*v.x + v.y*v.y + v.z*v.z + v.w*v.w;
    #pragma unroll
    for (int off = 32; off; off >>= 1) {
        s  += __shfl_xor(s, off);
        s2 += __shfl_xor(s2, off);
    }
    __shared__ float rs[4], rs2[4];
    int wave = threadIdx.x >> 6;
    if ((threadIdx.x & 63) == 0) { rs[wave] = s; rs2[wave] = s2; }
    __syncthreads();
    s  = rs[0] + rs[1] + rs[2] + rs[3];
    s2 = rs2[0] + rs2[1] + rs2[2] + rs2[3];
    float mean = s * (1.f / 1024.f);
    float var  = s2 * (1.f / 1024.f) - mean * mean;
    float rstd = rsqrtf(var + 1e-5f);
    float4 gg = ((const float4*)g)[threadIdx.x];
    float4 bb = ((const float4*)b)[threadIdx.x];
    ushort4v ov;
    ov[0] = f2bf((v.x - mean) * rstd * gg.x + bb.x);
    ov[1] = f2bf((v.y - mean) * rstd * gg.y + bb.y);
    ov[2] = f2bf((v.z - mean) * rstd * gg.z + bb.z);
    ov[3] = f2bf((v.w - mean) * rstd * gg.w + bb.w);
    ((ushort4v*)(out + row * 1024))[threadIdx.x] = ov;
}

// ---------------------------------------------------------------------------
// All-bf16 GEMM: C[M,N] = A[M,K] @ Bt[N,K]^T (+bias)(+resid)(+GELU).
// A bf16 [M][K], Bt bf16 [N][K] (both k-contiguous). f32 acc.
// Tile 128x128xK64, 4 waves. Staging: 4x16B contiguous loads per operand
// per thread, swizzled ds_write_b128. grid = (M/128, N/128).
// ---------------------------------------------------------------------------
template<bool OUT_BF16, bool GELU_ACT>
__global__ __launch_bounds__(256)
void gemm_bf16(const __hip_bfloat16* __restrict__ A,
               const __hip_bfloat16* __restrict__ Bt,
               const float* __restrict__ bias, const float* __restrict__ resid,
               void* __restrict__ Cout, int M, int N, int K)
{
    __shared__ unsigned char smem[32768];   // A 16KB | B 16KB, swizzled
    const int m0 = blockIdx.x * 128;
    const int n0 = blockIdx.y * 128;
    const int t    = threadIdx.x;
    const int lane = t & 63;
    const int wave = t >> 6;
    const int wm = (wave >> 1) * 64;
    const int wn = (wave & 1) * 64;

    f32x4 acc[4][4];
    #pragma unroll
    for (int i = 0; i < 4; ++i)
        #pragma unroll
        for (int j = 0; j < 4; ++j) {
            acc[i][j][0] = 0.f; acc[i][j][1] = 0.f; acc[i][j][2] = 0.f; acc[i][j][3] = 0.f;
        }

    const int srow = t >> 1;          // 0..127
    const int c0   = (t & 1) * 4;     // chunk base: 0 or 4 (16B chunks of 8 bf16)

    for (int k0 = 0; k0 < K; k0 += 64) {
        const short8* asrc = (const short8*)(A  + (size_t)(m0 + srow) * K + k0 + c0 * 8);
        const short8* bsrc = (const short8*)(Bt + (size_t)(n0 + srow) * K + k0 + c0 * 8);
        short8 av0 = asrc[0], av1 = asrc[1], av2 = asrc[2], av3 = asrc[3];
        short8 bv0 = bsrc[0], bv1 = bsrc[1], bv2 = bsrc[2], bv3 = bsrc[3];
        const int rbyte = srow * 128;
        const int sw    = (srow & 7) << 4;
        *(short8*)(smem + rbyte + (((c0+0)*16) ^ sw)) = av0;
        *(short8*)(smem + rbyte + (((c0+1)*16) ^ sw)) = av1;
        *(short8*)(smem + rbyte + (((c0+2)*16) ^ sw)) = av2;
        *(short8*)(smem + rbyte + (((c0+3)*16) ^ sw)) = av3;
        *(short8*)(smem + 16384 + rbyte + (((c0+0)*16) ^ sw)) = bv0;
        *(short8*)(smem + 16384 + rbyte + (((c0+1)*16) ^ sw)) = bv1;
        *(short8*)(smem + 16384 + rbyte + (((c0+2)*16) ^ sw)) = bv2;
        *(short8*)(smem + 16384 + rbyte + (((c0+3)*16) ^ sw)) = bv3;
        __syncthreads();
        const int lr = lane & 15;
        const int lk = lane >> 4;
        #pragma unroll
        for (int ks = 0; ks < 2; ++ks) {
            int chunk = ks * 4 + lk;
            short8 af[4], bfr[4];
            #pragma unroll
            for (int m = 0; m < 4; ++m) {
                int row = wm + m * 16 + lr;
                af[m] = *(const short8*)(smem + row * 128 + ((chunk * 16) ^ ((row & 7) << 4)));
            }
            #pragma unroll
            for (int n = 0; n < 4; ++n) {
                int nn = wn + n * 16 + lr;
                bfr[n] = *(const short8*)(smem + 16384 + nn * 128 + ((chunk * 16) ^ ((nn & 7) << 4)));
            }
            #pragma unroll
            for (int m = 0; m < 4; ++m)
                #pragma unroll
                for (int n = 0; n < 4; ++n)
                    acc[m][n] = __builtin_amdgcn_mfma_f32_16x16x32_bf16(af[m], bfr[n], acc[m][n], 0, 0, 0);
        }
        __syncthreads();
    }

    const int lr = lane & 15;
    const int lq = lane >> 4;
    #pragma unroll
    for (int n = 0; n < 4; ++n) {
        int col = n0 + wn + n * 16 + lr;
        float bv = bias ? bias[col] : 0.f;
        #pragma unroll
        for (int m = 0; m < 4; ++m) {
            int rbase = m0 + wm + m * 16 + lq * 4;
            #pragma unroll
            for (int j = 0; j < 4; ++j) {
                int row = rbase + j;
                float v = acc[m][n][j] + bv;
                if (resid) v += resid[(size_t)row * N + col];
                if (GELU_ACT) v = 0.5f * v * (1.f + erff(v * 0.70710678118654752f));
                if (OUT_BF16)
                    ((__hip_bfloat16*)Cout)[(size_t)row * N + col] = __float2bfloat16(v);
                else
                    ((float*)Cout)[(size_t)row * N + col] = v;
            }
        }
    }
}

// ---------------------------------------------------------------------------
// Causal attention v3 (r15, proven): no per-tile reductions, deferred denom.
// qkv f32 in, BF16 out (feeds proj GEMM A).
// ---------------------------------------------------------------------------
__global__ __launch_bounds__(256)
void attn_kernel(const float* __restrict__ qkv, __hip_bfloat16* __restrict__ y)
{
    __shared__ float Kt[64][65];   // [d][key]
    __shared__ float Vt[64][65];   // [key][d]
    __shared__ float Qs[16][64];   // [row][d]
    __shared__ float Ps[16][64];   // [row][key]

    const int qg   = blockIdx.x & 63;
    const int bh   = blockIdx.x >> 6;
    const int b    = bh >> 4;
    const int h    = bh & 15;
    const int wave = threadIdx.x >> 6;
    const int lane = threadIdx.x & 63;
    const int r0   = wave * 4;
    const int qbase = qg * 16;

    const size_t base_b = (size_t)b * 1024 * 3072;

    #pragma unroll
    for (int i = 0; i < 4; ++i)
        Qs[r0 + i][lane] =
            qkv[base_b + (size_t)(qbase + r0 + i) * 3072 + h * 64 + lane] * 0.125f;

    float o[4]    = {0.f, 0.f, 0.f, 0.f};
    float lsum[4] = {0.f, 0.f, 0.f, 0.f};

    const int ntiles = (qbase + 15) / 64 + 1;
    const int srow = threadIdx.x >> 2;
    const int sd   = (threadIdx.x & 3) * 16;

    for (int tile = 0; tile < ntiles; ++tile) {
        __syncthreads();
        const int kb = tile * 64;
        const float* kbase = qkv + base_b + (size_t)(kb + srow) * 3072 + 1024 + h * 64 + sd;
        const float* vbase = kbase + 1024;
        #pragma unroll
        for (int p = 0; p < 4; ++p) {
            float4 kv = *(const float4*)(kbase + p * 4);
            float4 vv = *(const float4*)(vbase + p * 4);
            Kt[sd + p*4 + 0][srow] = kv.x; Kt[sd + p*4 + 1][srow] = kv.y;
            Kt[sd + p*4 + 2][srow] = kv.z; Kt[sd + p*4 + 3][srow] = kv.w;
            Vt[srow][sd + p*4 + 0] = vv.x; Vt[srow][sd + p*4 + 1] = vv.y;
            Vt[srow][sd + p*4 + 2] = vv.z; Vt[srow][sd + p*4 + 3] = vv.w;
        }
        __syncthreads();

        float s0 = 0.f, s1 = 0.f, s2 = 0.f, s3 = 0.f;
        #pragma unroll
        for (int d0 = 0; d0 < 64; d0 += 4) {
            float k0 = Kt[d0 + 0][lane];
            float k1 = Kt[d0 + 1][lane];
            float k2 = Kt[d0 + 2][lane];
            float k3 = Kt[d0 + 3][lane];
            float4 q0 = *(const float4*)&Qs[r0 + 0][d0];
            float4 q1 = *(const float4*)&Qs[r0 + 1][d0];
            float4 q2 = *(const float4*)&Qs[r0 + 2][d0];
            float4 q3 = *(const float4*)&Qs[r0 + 3][d0];
            s0 += q0.x*k0 + q0.y*k1 + q0.z*k2 + q0.w*k3;
            s1 += q1.x*k0 + q1.y*k1 + q1.z*k2 + q1.w*k3;
            s2 += q2.x*k0 + q2.y*k1 + q2.z*k2 + q2.w*k3;
            s3 += q3.x*k0 + q3.y*k1 + q3.z*k2 + q3.w*k3;
        }
        float sv[4] = {s0, s1, s2, s3};
        const int kidx = kb + lane;
        #pragma unroll
        for (int r = 0; r < 4; ++r) {
            int q = qbase + r0 + r;
            float p = (kidx <= q) ? __expf(sv[r]) : 0.f;
            Ps[r0 + r][lane] = p;
            lsum[r] += p;
        }
        #pragma unroll
        for (int j0 = 0; j0 < 64; j0 += 4) {
            float v0 = Vt[j0 + 0][lane];
            float v1 = Vt[j0 + 1][lane];
            float v2 = Vt[j0 + 2][lane];
            float v3 = Vt[j0 + 3][lane];
            #pragma unroll
            for (int r = 0; r < 4; ++r) {
                float4 pf = *(const float4*)&Ps[r0 + r][j0];
                o[r] += pf.x*v0 + pf.y*v1 + pf.z*v2 + pf.w*v3;
            }
        }
    }

    #pragma unroll
    for (int r = 0; r < 4; ++r) {
        float l = lsum[r];
        #pragma unroll
        for (int off = 32; off; off >>= 1) l += __shfl_xor(l, off);
        y[(size_t)(b * 1024 + qbase + r0 + r) * 1024 + h * 64 + lane] =
            __float2bfloat16(o[r] / l);
    }
}

// ---------------------------------------------------------------------------
// Host launch.
// d_out: [0,100.7MB) = layer weights bf16-T (dead once logits written).
// ws: abuf_bf(4) | hbuf(8) | qkvb(24) | ybuf_bf(4) | mbuf_bf(16) = 56 MB;
//     w_lm bf16-T (65.5MB) at ws+4MB over dead hbuf/qkvb/... at the end.
// ---------------------------------------------------------------------------
extern "C" void kernel_launch(void* const* d_in, const int* in_sizes, int n_in,
                              void* d_out, int out_size, void* d_ws, size_t ws_size,
                              hipStream_t stream)
{
    (void)in_sizes; (void)n_in; (void)out_size; (void)ws_size;

    const int*   ids    = (const int*)d_in[0];
    const float* wte    = (const float*)d_in[1];
    const float* wpe    = (const float*)d_in[2];
    const float* ln1_g  = (const float*)d_in[3];
    const float* ln1_b  = (const float*)d_in[4];
    const float* w_qkv  = (const float*)d_in[5];
    const float* b_qkv  = (const float*)d_in[6];
    const float* w_proj = (const float*)d_in[7];
    const float* b_proj = (const float*)d_in[8];
    const float* ln2_g  = (const float*)d_in[9];
    const float* ln2_b  = (const float*)d_in[10];
    const float* w_fc1  = (const float*)d_in[11];
    const float* b_fc1  = (const float*)d_in[12];
    const float* w_fc2  = (const float*)d_in[13];
    const float* b_fc2  = (const float*)d_in[14];
    const float* lnf_g  = (const float*)d_in[15];
    const float* lnf_b  = (const float*)d_in[16];
    const float* w_lm   = (const float*)d_in[17];

    char* ws = (char*)d_ws;
    __hip_bfloat16* abuf_bf = (__hip_bfloat16*)ws;                    // 4 MB
    float*          hbuf    = (float*)(ws + (4u<<20));                // 8 MB
    float*          qkvb    = (float*)(ws + (12u<<20));               // 24 MB
    __hip_bfloat16* ybuf_bf = (__hip_bfloat16*)(ws + (36u<<20));      // 4 MB
    __hip_bfloat16* mbuf_bf = (__hip_bfloat16*)(ws + (40u<<20));      // 16 MB
    __hip_bfloat16* wlm_bf  = (__hip_bfloat16*)(ws + (4u<<20));       // 65.5 MB (end-of-run)

    __hip_bfloat16* wq_bf = (__hip_bfloat16*)d_out;                   // 4x1024x3072
    __hip_bfloat16* wp_bf = wq_bf + (size_t)4*1024*3072;              // 4x1024x1024
    __hip_bfloat16* w1_bf = wp_bf + (size_t)4*1024*1024;              // 4x1024x4096
    __hip_bfloat16* w2_bf = w1_bf + (size_t)4*1024*4096;              // 4x4096x1024

    float* out = (float*)d_out;   // f32 logits [2048][32000]

    // ---- weight transpose-cast (layer weights -> d_out) ----
    tc_kernel<<<dim3(16, 48, 4), 256, 0, stream>>>(w_qkv,  wq_bf, 3072, 1024);
    tc_kernel<<<dim3(16, 16, 4), 256, 0, stream>>>(w_proj, wp_bf, 1024, 1024);
    tc_kernel<<<dim3(16, 64, 4), 256, 0, stream>>>(w_fc1,  w1_bf, 4096, 1024);
    tc_kernel<<<dim3(64, 16, 4), 256, 0, stream>>>(w_fc2,  w2_bf, 1024, 4096);

    embed_kernel<<<2048, 256, 0, stream>>>(ids, wte, wpe, hbuf);

    for (int l = 0; l < 4; ++l) {
        ln_kernel<<<2048, 256, 0, stream>>>(hbuf, ln1_g + l*1024, ln1_b + l*1024, abuf_bf);
        gemm_bf16<false,false><<<dim3(16, 24), 256, 0, stream>>>(
            abuf_bf, wq_bf + (size_t)l*1024*3072, b_qkv + l*3072, nullptr, qkvb, 2048, 3072, 1024);
        attn_kernel<<<2048, 256, 0, stream>>>(qkvb, ybuf_bf);
        gemm_bf16<false,false><<<dim3(16, 8), 256, 0, stream>>>(
            ybuf_bf, wp_bf + (size_t)l*1024*1024, b_proj + l*1024, hbuf, hbuf, 2048, 1024, 1024);
        ln_kernel<<<2048, 256, 0, stream>>>(hbuf, ln2_g + l*1024, ln2_b + l*1024, abuf_bf);
        gemm_bf16<true,true><<<dim3(16, 32), 256, 0, stream>>>(
            abuf_bf, w1_bf + (size_t)l*1024*4096, b_fc1 + l*4096, nullptr, mbuf_bf, 2048, 4096, 1024);
        gemm_bf16<false,false><<<dim3(16, 8), 256, 0, stream>>>(
            mbuf_bf, w2_bf + (size_t)l*4096*1024, b_fc2 + l*1024, hbuf, hbuf, 2048, 1024, 4096);
    }

    ln_kernel<<<2048, 256, 0, stream>>>(hbuf, lnf_g, lnf_b, abuf_bf);
    // hbuf (and all other f32 transients) now dead: convert w_lm over them.
    tc_kernel<<<dim3(16, 500, 1), 256, 0, stream>>>(w_lm, wlm_bf, 32000, 1024);
    gemm_bf16<false,false><<<dim3(16, 250), 256, 0, stream>>>(
        abuf_bf, wlm_bf, nullptr, nullptr, out, 2048, 32000, 1024);
}

// Round 18
// 1290.170 us; speedup vs baseline: 8.9289x; 1.6157x over previous
//
#include <hip/hip_runtime.h>
#include <hip/hip_bf16.h>
#include <math.h>

typedef __attribute__((ext_vector_type(4))) float f32x4;
typedef __attribute__((ext_vector_type(8))) short short8;
typedef __attribute__((ext_vector_type(4))) unsigned short ushort4v;

__device__ __forceinline__ unsigned short f2bf(float f) {
    return __builtin_bit_cast(unsigned short, __float2bfloat16(f));
}

// ---------------------------------------------------------------------------
// Transpose-cast: in f32 [K][N] (layer z) -> out bf16 [N][K] (k-contiguous)
// ---------------------------------------------------------------------------
__global__ __launch_bounds__(256)
void tc_kernel(const float* __restrict__ in, __hip_bfloat16* __restrict__ out,
               int N, int K)
{
    __shared__ float tile[64][65];
    const size_t loff = (size_t)blockIdx.z * K * N;
    const int k0 = blockIdx.x * 64, n0 = blockIdx.y * 64;
    const int t = threadIdx.x;
    {
        int kk = t >> 2, nb = (t & 3) * 16;
        const float* src = in + loff + (size_t)(k0 + kk) * N + n0 + nb;
        #pragma unroll
        for (int j = 0; j < 4; ++j) {
            float4 v = *(const float4*)(src + j * 4);
            tile[kk][nb + j*4 + 0] = v.x; tile[kk][nb + j*4 + 1] = v.y;
            tile[kk][nb + j*4 + 2] = v.z; tile[kk][nb + j*4 + 3] = v.w;
        }
    }
    __syncthreads();
    {
        int nn = t >> 2, kb = (t & 3) * 16;
        __hip_bfloat16* dst = out + loff + (size_t)(n0 + nn) * K + k0 + kb;
        short8 w0, w1;
        #pragma unroll
        for (int j = 0; j < 8; ++j) w0[j] = (short)f2bf(tile[kb + j][nn]);
        #pragma unroll
        for (int j = 0; j < 8; ++j) w1[j] = (short)f2bf(tile[kb + 8 + j][nn]);
        *(short8*)dst = w0;
        *(short8*)(dst + 8) = w1;
    }
}

// ---------------------------------------------------------------------------
// Embedding (f32 out)
// ---------------------------------------------------------------------------
__global__ __launch_bounds__(256)
void embed_kernel(const int* __restrict__ ids, const float* __restrict__ wte,
                  const float* __restrict__ wpe, float* __restrict__ h)
{
    int row  = blockIdx.x;
    int tpos = row & 1023;
    int id   = ids[row];
    float4 a = ((const float4*)(wte + (size_t)id * 1024))[threadIdx.x];
    float4 p = ((const float4*)(wpe + (size_t)tpos * 1024))[threadIdx.x];
    float4 o; o.x = a.x + p.x; o.y = a.y + p.y; o.z = a.z + p.z; o.w = a.w + p.w;
    ((float4*)(h + (size_t)row * 1024))[threadIdx.x] = o;
}

// ---------------------------------------------------------------------------
// LayerNorm: f32 in, BF16 out
// ---------------------------------------------------------------------------
__global__ __launch_bounds__(256)
void ln_kernel(const float* __restrict__ x, const float* __restrict__ g,
               const float* __restrict__ b, __hip_bfloat16* __restrict__ out)
{
    size_t row = blockIdx.x;
    float4 v = ((const float4*)(x + row * 1024))[threadIdx.x];
    float s  = v.x + v.y + v.z + v.w;
    float s2 = v.x*v.x + v.y*v.y + v.z*v.z + v.w*v.w;
    #pragma unroll
    for (int off = 32; off; off >>= 1) {
        s  += __shfl_xor(s, off);
        s2 += __shfl_xor(s2, off);
    }
    __shared__ float rs[4], rs2[4];
    int wave = threadIdx.x >> 6;
    if ((threadIdx.x & 63) == 0) { rs[wave] = s; rs2[wave] = s2; }
    __syncthreads();
    s  = rs[0] + rs[1] + rs[2] + rs[3];
    s2 = rs2[0] + rs2[1] + rs2[2] + rs2[3];
    float mean = s * (1.f / 1024.f);
    float var  = s2 * (1.f / 1024.f) - mean * mean;
    float rstd = rsqrtf(var + 1e-5f);
    float4 gg = ((const float4*)g)[threadIdx.x];
    float4 bb = ((const float4*)b)[threadIdx.x];
    ushort4v ov;
    ov[0] = f2bf((v.x - mean) * rstd * gg.x + bb.x);
    ov[1] = f2bf((v.y - mean) * rstd * gg.y + bb.y);
    ov[2] = f2bf((v.z - mean) * rstd * gg.z + bb.z);
    ov[3] = f2bf((v.w - mean) * rstd * gg.w + bb.w);
    ((ushort4v*)(out + row * 1024))[threadIdx.x] = ov;
}

// ---------------------------------------------------------------------------
// All-bf16 GEMM (r16, proven): C = A[M,K] @ Bt[N,K]^T (+bias)(+resid)(+GELU)
// ---------------------------------------------------------------------------
template<bool OUT_BF16, bool GELU_ACT>
__global__ __launch_bounds__(256)
void gemm_bf16(const __hip_bfloat16* __restrict__ A,
               const __hip_bfloat16* __restrict__ Bt,
               const float* __restrict__ bias, const float* __restrict__ resid,
               void* __restrict__ Cout, int M, int N, int K)
{
    __shared__ unsigned char smem[32768];
    const int m0 = blockIdx.x * 128;
    const int n0 = blockIdx.y * 128;
    const int t    = threadIdx.x;
    const int lane = t & 63;
    const int wave = t >> 6;
    const int wm = (wave >> 1) * 64;
    const int wn = (wave & 1) * 64;

    f32x4 acc[4][4];
    #pragma unroll
    for (int i = 0; i < 4; ++i)
        #pragma unroll
        for (int j = 0; j < 4; ++j) {
            acc[i][j][0] = 0.f; acc[i][j][1] = 0.f; acc[i][j][2] = 0.f; acc[i][j][3] = 0.f;
        }

    const int srow = t >> 1;
    const int c0   = (t & 1) * 4;

    for (int k0 = 0; k0 < K; k0 += 64) {
        const short8* asrc = (const short8*)(A  + (size_t)(m0 + srow) * K + k0 + c0 * 8);
        const short8* bsrc = (const short8*)(Bt + (size_t)(n0 + srow) * K + k0 + c0 * 8);
        short8 av0 = asrc[0], av1 = asrc[1], av2 = asrc[2], av3 = asrc[3];
        short8 bv0 = bsrc[0], bv1 = bsrc[1], bv2 = bsrc[2], bv3 = bsrc[3];
        const int rbyte = srow * 128;
        const int sw    = (srow & 7) << 4;
        *(short8*)(smem + rbyte + (((c0+0)*16) ^ sw)) = av0;
        *(short8*)(smem + rbyte + (((c0+1)*16) ^ sw)) = av1;
        *(short8*)(smem + rbyte + (((c0+2)*16) ^ sw)) = av2;
        *(short8*)(smem + rbyte + (((c0+3)*16) ^ sw)) = av3;
        *(short8*)(smem + 16384 + rbyte + (((c0+0)*16) ^ sw)) = bv0;
        *(short8*)(smem + 16384 + rbyte + (((c0+1)*16) ^ sw)) = bv1;
        *(short8*)(smem + 16384 + rbyte + (((c0+2)*16) ^ sw)) = bv2;
        *(short8*)(smem + 16384 + rbyte + (((c0+3)*16) ^ sw)) = bv3;
        __syncthreads();
        const int lr = lane & 15;
        const int lk = lane >> 4;
        #pragma unroll
        for (int ks = 0; ks < 2; ++ks) {
            int chunk = ks * 4 + lk;
            short8 af[4], bfr[4];
            #pragma unroll
            for (int m = 0; m < 4; ++m) {
                int row = wm + m * 16 + lr;
                af[m] = *(const short8*)(smem + row * 128 + ((chunk * 16) ^ ((row & 7) << 4)));
            }
            #pragma unroll
            for (int n = 0; n < 4; ++n) {
                int nn = wn + n * 16 + lr;
                bfr[n] = *(const short8*)(smem + 16384 + nn * 128 + ((chunk * 16) ^ ((nn & 7) << 4)));
            }
            #pragma unroll
            for (int m = 0; m < 4; ++m)
                #pragma unroll
                for (int n = 0; n < 4; ++n)
                    acc[m][n] = __builtin_amdgcn_mfma_f32_16x16x32_bf16(af[m], bfr[n], acc[m][n], 0, 0, 0);
        }
        __syncthreads();
    }

    const int lr = lane & 15;
    const int lq = lane >> 4;
    #pragma unroll
    for (int n = 0; n < 4; ++n) {
        int col = n0 + wn + n * 16 + lr;
        float bv = bias ? bias[col] : 0.f;
        #pragma unroll
        for (int m = 0; m < 4; ++m) {
            int rbase = m0 + wm + m * 16 + lq * 4;
            #pragma unroll
            for (int j = 0; j < 4; ++j) {
                int row = rbase + j;
                float v = acc[m][n][j] + bv;
                if (resid) v += resid[(size_t)row * N + col];
                if (GELU_ACT) v = 0.5f * v * (1.f + erff(v * 0.70710678118654752f));
                if (OUT_BF16)
                    ((__hip_bfloat16*)Cout)[(size_t)row * N + col] = __float2bfloat16(v);
                else
                    ((float*)Cout)[(size_t)row * N + col] = v;
            }
        }
    }
}

// ---------------------------------------------------------------------------
// MFMA causal attention (r17 + Q-staging fix: full 64-wide tile now staged).
// ---------------------------------------------------------------------------
__global__ __launch_bounds__(256)
void attn_mfma(const __hip_bfloat16* __restrict__ qkv,
               __hip_bfloat16* __restrict__ y)
{
    __shared__ short Qs[64][72];            // [q][d]
    __shared__ short Ps[64][72];            // [q][key]
    __shared__ unsigned char Kl[8192];      // [key][d] bf16, XOR-swizzled
    __shared__ short Vt[64][72];            // [d][key]

    const int bid = blockIdx.x;
    const int p   = bid >> 5;
    const int qt  = (p < 8) ? (15 - 2 * p) : (2 * (p - 8));
    const int bh  = bid & 31;
    const int b = bh >> 4, h = bh & 15;
    const int t = threadIdx.x, lane = t & 63, w = t >> 6;
    const int lr = lane & 15, lg = lane >> 4;
    const size_t base = (size_t)b * 1024 * 3072;
    const int qbase = qt * 64;

    // ---- stage Q tile (64 x 64 bf16): TWO short8 per thread (fix) ----
    {
        int row = t >> 2, c = t & 3;
        const short8* qsrc = (const short8*)(qkv + base + (size_t)(qbase + row) * 3072 + h * 64);
        *(short8*)&Qs[row][c * 8]      = qsrc[c];        // d in [0,32)
        *(short8*)&Qs[row][c * 8 + 32] = qsrc[c + 4];    // d in [32,64)
    }
    __syncthreads();

    short8 aq0 = *(const short8*)&Qs[w * 16 + lr][0 * 32 + lg * 8];
    short8 aq1 = *(const short8*)&Qs[w * 16 + lr][1 * 32 + lg * 8];

    f32x4 oacc[4];
    #pragma unroll
    for (int dt = 0; dt < 4; ++dt) { oacc[dt][0]=0.f; oacc[dt][1]=0.f; oacc[dt][2]=0.f; oacc[dt][3]=0.f; }
    float lsum[4] = {0.f, 0.f, 0.f, 0.f};

    const int ntiles = qt + 1;
    const int kkey = t >> 2, kc = t & 3;
    const int vkey = t & 63, vc = t >> 6;

    for (int tile = 0; tile < ntiles; ++tile) {
        const int kb = tile * 64;
        {
            const short8* ksrc = (const short8*)(qkv + base + (size_t)(kb + kkey) * 3072 + 1024 + h * 64);
            short8 k0 = ksrc[kc], k1 = ksrc[kc + 4];
            int rb = kkey * 128, sw = (kkey & 7) << 4;
            *(short8*)(Kl + rb + ((kc * 16) ^ sw)) = k0;
            *(short8*)(Kl + rb + (((kc + 4) * 16) ^ sw)) = k1;

            const short8* vsrc = (const short8*)(qkv + base + (size_t)(kb + vkey) * 3072 + 2048 + h * 64);
            short8 v0 = vsrc[vc], v1 = vsrc[vc + 4];
            #pragma unroll
            for (int j = 0; j < 8; ++j) Vt[vc * 8 + j][vkey] = v0[j];
            #pragma unroll
            for (int j = 0; j < 8; ++j) Vt[(vc + 4) * 8 + j][vkey] = v1[j];
        }
        __syncthreads();

        // ---- S = Q @ K^T ----
        f32x4 sacc[4];
        #pragma unroll
        for (int kt = 0; kt < 4; ++kt) { sacc[kt][0]=0.f; sacc[kt][1]=0.f; sacc[kt][2]=0.f; sacc[kt][3]=0.f; }
        #pragma unroll
        for (int ks = 0; ks < 2; ++ks) {
            short8 aq = ks ? aq1 : aq0;
            #pragma unroll
            for (int kt = 0; kt < 4; ++kt) {
                int krow = kt * 16 + lr;
                short8 bk = *(const short8*)(Kl + krow * 128 + (((ks * 4 + lg) * 16) ^ ((krow & 7) << 4)));
                sacc[kt] = __builtin_amdgcn_mfma_f32_16x16x32_bf16(aq, bk, sacc[kt], 0, 0, 0);
            }
        }

        // ---- no-max softmax + P->bf16->LDS (deferred denominator) ----
        #pragma unroll
        for (int kt = 0; kt < 4; ++kt) {
            int key = kb + kt * 16 + lr;
            #pragma unroll
            for (int j = 0; j < 4; ++j) {
                int q = qbase + w * 16 + lg * 4 + j;
                float pv = (key <= q) ? __expf(sacc[kt][j] * 0.125f) : 0.f;
                lsum[j] += pv;
                Ps[w * 16 + lg * 4 + j][kt * 16 + lr] = (short)f2bf(pv);
            }
        }

        // ---- O += P @ V ----
        #pragma unroll
        for (int ks = 0; ks < 2; ++ks) {
            short8 ap = *(const short8*)&Ps[w * 16 + lr][ks * 32 + lg * 8];
            #pragma unroll
            for (int dt = 0; dt < 4; ++dt) {
                short8 bv = *(const short8*)&Vt[dt * 16 + lr][ks * 32 + lg * 8];
                oacc[dt] = __builtin_amdgcn_mfma_f32_16x16x32_bf16(ap, bv, oacc[dt], 0, 0, 0);
            }
        }
        __syncthreads();
    }

    #pragma unroll
    for (int j = 0; j < 4; ++j) {
        float l = lsum[j];
        l += __shfl_xor(l, 1); l += __shfl_xor(l, 2);
        l += __shfl_xor(l, 4); l += __shfl_xor(l, 8);
        float inv = 1.f / l;
        int qrow = qbase + w * 16 + lg * 4 + j;
        __hip_bfloat16* dst = y + (size_t)(b * 1024 + qrow) * 1024 + h * 64;
        #pragma unroll
        for (int dt = 0; dt < 4; ++dt)
            dst[dt * 16 + lr] = __float2bfloat16(oacc[dt][j] * inv);
    }
}

// ---------------------------------------------------------------------------
// Host launch (r17 layout).
// ---------------------------------------------------------------------------
extern "C" void kernel_launch(void* const* d_in, const int* in_sizes, int n_in,
                              void* d_out, int out_size, void* d_ws, size_t ws_size,
                              hipStream_t stream)
{
    (void)in_sizes; (void)n_in; (void)out_size; (void)ws_size;

    const int*   ids    = (const int*)d_in[0];
    const float* wte    = (const float*)d_in[1];
    const float* wpe    = (const float*)d_in[2];
    const float* ln1_g  = (const float*)d_in[3];
    const float* ln1_b  = (const float*)d_in[4];
    const float* w_qkv  = (const float*)d_in[5];
    const float* b_qkv  = (const float*)d_in[6];
    const float* w_proj = (const float*)d_in[7];
    const float* b_proj = (const float*)d_in[8];
    const float* ln2_g  = (const float*)d_in[9];
    const float* ln2_b  = (const float*)d_in[10];
    const float* w_fc1  = (const float*)d_in[11];
    const float* b_fc1  = (const float*)d_in[12];
    const float* w_fc2  = (const float*)d_in[13];
    const float* b_fc2  = (const float*)d_in[14];
    const float* lnf_g  = (const float*)d_in[15];
    const float* lnf_b  = (const float*)d_in[16];
    const float* w_lm   = (const float*)d_in[17];

    char* ws = (char*)d_ws;
    __hip_bfloat16* abuf_bf = (__hip_bfloat16*)ws;                    // 4 MB
    float*          hbuf    = (float*)(ws + (4u<<20));                // 8 MB
    __hip_bfloat16* qkvb_bf = (__hip_bfloat16*)(ws + (12u<<20));      // 12 MB
    __hip_bfloat16* ybuf_bf = (__hip_bfloat16*)(ws + (24u<<20));      // 4 MB
    __hip_bfloat16* mbuf_bf = (__hip_bfloat16*)(ws + (28u<<20));      // 16 MB
    __hip_bfloat16* wlm_bf  = (__hip_bfloat16*)(ws + (4u<<20));       // 65.5 MB (end)

    __hip_bfloat16* wq_bf = (__hip_bfloat16*)d_out;
    __hip_bfloat16* wp_bf = wq_bf + (size_t)4*1024*3072;
    __hip_bfloat16* w1_bf = wp_bf + (size_t)4*1024*1024;
    __hip_bfloat16* w2_bf = w1_bf + (size_t)4*1024*4096;

    float* out = (float*)d_out;   // f32 logits

    tc_kernel<<<dim3(16, 48, 4), 256, 0, stream>>>(w_qkv,  wq_bf, 3072, 1024);
    tc_kernel<<<dim3(16, 16, 4), 256, 0, stream>>>(w_proj, wp_bf, 1024, 1024);
    tc_kernel<<<dim3(16, 64, 4), 256, 0, stream>>>(w_fc1,  w1_bf, 4096, 1024);
    tc_kernel<<<dim3(64, 16, 4), 256, 0, stream>>>(w_fc2,  w2_bf, 1024, 4096);

    embed_kernel<<<2048, 256, 0, stream>>>(ids, wte, wpe, hbuf);

    for (int l = 0; l < 4; ++l) {
        ln_kernel<<<2048, 256, 0, stream>>>(hbuf, ln1_g + l*1024, ln1_b + l*1024, abuf_bf);
        gemm_bf16<true,false><<<dim3(16, 24), 256, 0, stream>>>(
            abuf_bf, wq_bf + (size_t)l*1024*3072, b_qkv + l*3072, nullptr, qkvb_bf, 2048, 3072, 1024);
        attn_mfma<<<512, 256, 0, stream>>>(qkvb_bf, ybuf_bf);
        gemm_bf16<false,false><<<dim3(16, 8), 256, 0, stream>>>(
            ybuf_bf, wp_bf + (size_t)l*1024*1024, b_proj + l*1024, hbuf, hbuf, 2048, 1024, 1024);
        ln_kernel<<<2048, 256, 0, stream>>>(hbuf, ln2_g + l*1024, ln2_b + l*1024, abuf_bf);
        gemm_bf16<true,true><<<dim3(16, 32), 256, 0, stream>>>(
            abuf_bf, w1_bf + (size_t)l*1024*4096, b_fc1 + l*4096, nullptr, mbuf_bf, 2048, 4096, 1024);
        gemm_bf16<false,false><<<dim3(16, 8), 256, 0, stream>>>(
            mbuf_bf, w2_bf + (size_t)l*4096*1024, b_fc2 + l*1024, hbuf, hbuf, 2048, 1024, 4096);
    }

    ln_kernel<<<2048, 256, 0, stream>>>(hbuf, lnf_g, lnf_b, abuf_bf);
    tc_kernel<<<dim3(16, 500, 1), 256, 0, stream>>>(w_lm, wlm_bf, 32000, 1024);
    gemm_bf16<false,false><<<dim3(16, 250), 256, 0, stream>>>(
        abuf_bf, wlm_bf, nullptr, nullptr, out, 2048, 32000, 1024);
}

// Round 19
// 1206.854 us; speedup vs baseline: 9.5453x; 1.0690x over previous
//
#include <hip/hip_runtime.h>
#include <hip/hip_bf16.h>
#include <math.h>

typedef __attribute__((ext_vector_type(4))) float f32x4;
typedef __attribute__((ext_vector_type(8))) short short8;
typedef __attribute__((ext_vector_type(4))) unsigned short ushort4v;

__device__ __forceinline__ unsigned short f2bf(float f) {
    return __builtin_bit_cast(unsigned short, __float2bfloat16(f));
}

__device__ __forceinline__ void gload16(const void* g, void* l) {
    __builtin_amdgcn_global_load_lds(
        (const __attribute__((address_space(1))) unsigned int*)g,
        (__attribute__((address_space(3))) unsigned int*)l, 16, 0, 0);
}

// ---------------------------------------------------------------------------
// Transpose-cast: in f32 [K][N] (layer z) -> out bf16 [N][K] (k-contiguous)
// ---------------------------------------------------------------------------
__global__ __launch_bounds__(256)
void tc_kernel(const float* __restrict__ in, __hip_bfloat16* __restrict__ out,
               int N, int K)
{
    __shared__ float tile[64][65];
    const size_t loff = (size_t)blockIdx.z * K * N;
    const int k0 = blockIdx.x * 64, n0 = blockIdx.y * 64;
    const int t = threadIdx.x;
    {
        int kk = t >> 2, nb = (t & 3) * 16;
        const float* src = in + loff + (size_t)(k0 + kk) * N + n0 + nb;
        #pragma unroll
        for (int j = 0; j < 4; ++j) {
            float4 v = *(const float4*)(src + j * 4);
            tile[kk][nb + j*4 + 0] = v.x; tile[kk][nb + j*4 + 1] = v.y;
            tile[kk][nb + j*4 + 2] = v.z; tile[kk][nb + j*4 + 3] = v.w;
        }
    }
    __syncthreads();
    {
        int nn = t >> 2, kb = (t & 3) * 16;
        __hip_bfloat16* dst = out + loff + (size_t)(n0 + nn) * K + k0 + kb;
        short8 w0, w1;
        #pragma unroll
        for (int j = 0; j < 8; ++j) w0[j] = (short)f2bf(tile[kb + j][nn]);
        #pragma unroll
        for (int j = 0; j < 8; ++j) w1[j] = (short)f2bf(tile[kb + 8 + j][nn]);
        *(short8*)dst = w0;
        *(short8*)(dst + 8) = w1;
    }
}

// ---------------------------------------------------------------------------
// Embedding (f32 out)
// ---------------------------------------------------------------------------
__global__ __launch_bounds__(256)
void embed_kernel(const int* __restrict__ ids, const float* __restrict__ wte,
                  const float* __restrict__ wpe, float* __restrict__ h)
{
    int row  = blockIdx.x;
    int tpos = row & 1023;
    int id   = ids[row];
    float4 a = ((const float4*)(wte + (size_t)id * 1024))[threadIdx.x];
    float4 p = ((const float4*)(wpe + (size_t)tpos * 1024))[threadIdx.x];
    float4 o; o.x = a.x + p.x; o.y = a.y + p.y; o.z = a.z + p.z; o.w = a.w + p.w;
    ((float4*)(h + (size_t)row * 1024))[threadIdx.x] = o;
}

// ---------------------------------------------------------------------------
// LayerNorm: f32 in, BF16 out
// ---------------------------------------------------------------------------
__global__ __launch_bounds__(256)
void ln_kernel(const float* __restrict__ x, const float* __restrict__ g,
               const float* __restrict__ b, __hip_bfloat16* __restrict__ out)
{
    size_t row = blockIdx.x;
    float4 v = ((const float4*)(x + row * 1024))[threadIdx.x];
    float s  = v.x + v.y + v.z + v.w;
    float s2 = v.x*v.x + v.y*v.y + v.z*v.z + v.w*v.w;
    #pragma unroll
    for (int off = 32; off; off >>= 1) {
        s  += __shfl_xor(s, off);
        s2 += __shfl_xor(s2, off);
    }
    __shared__ float rs[4], rs2[4];
    int wave = threadIdx.x >> 6;
    if ((threadIdx.x & 63) == 0) { rs[wave] = s; rs2[wave] = s2; }
    __syncthreads();
    s  = rs[0] + rs[1] + rs[2] + rs[3];
    s2 = rs2[0] + rs2[1] + rs2[2] + rs2[3];
    float mean = s * (1.f / 1024.f);
    float var  = s2 * (1.f / 1024.f) - mean * mean;
    float rstd = rsqrtf(var + 1e-5f);
    float4 gg = ((const float4*)g)[threadIdx.x];
    float4 bb = ((const float4*)b)[threadIdx.x];
    ushort4v ov;
    ov[0] = f2bf((v.x - mean) * rstd * gg.x + bb.x);
    ov[1] = f2bf((v.y - mean) * rstd * gg.y + bb.y);
    ov[2] = f2bf((v.z - mean) * rstd * gg.z + bb.z);
    ov[3] = f2bf((v.w - mean) * rstd * gg.w + bb.w);
    ((ushort4v*)(out + row * 1024))[threadIdx.x] = ov;
}

// ---------------------------------------------------------------------------
// All-bf16 GEMM, global_load_lds staging (m97 structure).
// LDS layout identical to r18's proven XOR-swizzled layout: the DMA writes
// linearly (lane -> base + lane*16) and the per-lane GLOBAL chunk index is
// pre-swizzled (c = (l&7) ^ (l>>3)), so landed bytes match r18 exactly.
// Fragment reads and MFMA loop byte-identical to r18.
// ---------------------------------------------------------------------------
template<bool OUT_BF16, bool GELU_ACT>
__global__ __launch_bounds__(256)
void gemm_bf16(const __hip_bfloat16* __restrict__ A,
               const __hip_bfloat16* __restrict__ Bt,
               const float* __restrict__ bias, const float* __restrict__ resid,
               void* __restrict__ Cout, int M, int N, int K)
{
    __shared__ unsigned char smem[32768];
    const int m0 = blockIdx.x * 128;
    const int n0 = blockIdx.y * 128;
    const int t    = threadIdx.x;
    const int lane = t & 63;
    const int wave = t >> 6;
    const int wm = (wave >> 1) * 64;
    const int wn = (wave & 1) * 64;

    f32x4 acc[4][4];
    #pragma unroll
    for (int i = 0; i < 4; ++i)
        #pragma unroll
        for (int j = 0; j < 4; ++j) {
            acc[i][j][0] = 0.f; acc[i][j][1] = 0.f; acc[i][j][2] = 0.f; acc[i][j][3] = 0.f;
        }

    // ---- staging addressing (hoisted out of the K loop) ----
    const int l8 = lane >> 3;                 // 0..7 (row within 8-row group)
    const int lc = (lane & 7) ^ l8;           // pre-swizzled global chunk idx
    const __hip_bfloat16* agp[4];
    const __hip_bfloat16* bgp[4];
    void* alds[4];
    void* blds[4];
    #pragma unroll
    for (int i = 0; i < 4; ++i) {
        int row = wave * 32 + i * 8 + l8;     // row&7 == l8
        agp[i] = A  + (size_t)(m0 + row) * K + lc * 8;
        bgp[i] = Bt + (size_t)(n0 + row) * K + lc * 8;
        alds[i] = (void*)(smem + (wave * 32 + i * 8) * 128);          // wave-uniform
        blds[i] = (void*)(smem + 16384 + (wave * 32 + i * 8) * 128);  // wave-uniform
    }

    for (int k0 = 0; k0 < K; k0 += 64) {
        #pragma unroll
        for (int i = 0; i < 4; ++i) {
            gload16(agp[i] + k0, alds[i]);
            gload16(bgp[i] + k0, blds[i]);
        }
        __syncthreads();   // drains vmcnt (global_load_lds) for all waves
        const int lr = lane & 15;
        const int lk = lane >> 4;
        #pragma unroll
        for (int ks = 0; ks < 2; ++ks) {
            int chunk = ks * 4 + lk;
            short8 af[4], bfr[4];
            #pragma unroll
            for (int m = 0; m < 4; ++m) {
                int row = wm + m * 16 + lr;
                af[m] = *(const short8*)(smem + row * 128 + ((chunk * 16) ^ ((row & 7) << 4)));
            }
            #pragma unroll
            for (int n = 0; n < 4; ++n) {
                int nn = wn + n * 16 + lr;
                bfr[n] = *(const short8*)(smem + 16384 + nn * 128 + ((chunk * 16) ^ ((nn & 7) << 4)));
            }
            #pragma unroll
            for (int m = 0; m < 4; ++m)
                #pragma unroll
                for (int n = 0; n < 4; ++n)
                    acc[m][n] = __builtin_amdgcn_mfma_f32_16x16x32_bf16(af[m], bfr[n], acc[m][n], 0, 0, 0);
        }
        __syncthreads();
    }

    const int lr = lane & 15;
    const int lq = lane >> 4;
    #pragma unroll
    for (int n = 0; n < 4; ++n) {
        int col = n0 + wn + n * 16 + lr;
        float bv = bias ? bias[col] : 0.f;
        #pragma unroll
        for (int m = 0; m < 4; ++m) {
            int rbase = m0 + wm + m * 16 + lq * 4;
            #pragma unroll
            for (int j = 0; j < 4; ++j) {
                int row = rbase + j;
                float v = acc[m][n][j] + bv;
                if (resid) v += resid[(size_t)row * N + col];
                if (GELU_ACT) v = 0.5f * v * (1.f + erff(v * 0.70710678118654752f));
                if (OUT_BF16)
                    ((__hip_bfloat16*)Cout)[(size_t)row * N + col] = __float2bfloat16(v);
                else
                    ((float*)Cout)[(size_t)row * N + col] = v;
            }
        }
    }
}

// ---------------------------------------------------------------------------
// MFMA causal attention (r18, proven)
// ---------------------------------------------------------------------------
__global__ __launch_bounds__(256)
void attn_mfma(const __hip_bfloat16* __restrict__ qkv,
               __hip_bfloat16* __restrict__ y)
{
    __shared__ short Qs[64][72];
    __shared__ short Ps[64][72];
    __shared__ unsigned char Kl[8192];
    __shared__ short Vt[64][72];

    const int bid = blockIdx.x;
    const int p   = bid >> 5;
    const int qt  = (p < 8) ? (15 - 2 * p) : (2 * (p - 8));
    const int bh  = bid & 31;
    const int b = bh >> 4, h = bh & 15;
    const int t = threadIdx.x, lane = t & 63, w = t >> 6;
    const int lr = lane & 15, lg = lane >> 4;
    const size_t base = (size_t)b * 1024 * 3072;
    const int qbase = qt * 64;

    {
        int row = t >> 2, c = t & 3;
        const short8* qsrc = (const short8*)(qkv + base + (size_t)(qbase + row) * 3072 + h * 64);
        *(short8*)&Qs[row][c * 8]      = qsrc[c];
        *(short8*)&Qs[row][c * 8 + 32] = qsrc[c + 4];
    }
    __syncthreads();

    short8 aq0 = *(const short8*)&Qs[w * 16 + lr][0 * 32 + lg * 8];
    short8 aq1 = *(const short8*)&Qs[w * 16 + lr][1 * 32 + lg * 8];

    f32x4 oacc[4];
    #pragma unroll
    for (int dt = 0; dt < 4; ++dt) { oacc[dt][0]=0.f; oacc[dt][1]=0.f; oacc[dt][2]=0.f; oacc[dt][3]=0.f; }
    float lsum[4] = {0.f, 0.f, 0.f, 0.f};

    const int ntiles = qt + 1;
    const int kkey = t >> 2, kc = t & 3;
    const int vkey = t & 63, vc = t >> 6;

    for (int tile = 0; tile < ntiles; ++tile) {
        const int kb = tile * 64;
        {
            const short8* ksrc = (const short8*)(qkv + base + (size_t)(kb + kkey) * 3072 + 1024 + h * 64);
            short8 k0 = ksrc[kc], k1 = ksrc[kc + 4];
            int rb = kkey * 128, sw = (kkey & 7) << 4;
            *(short8*)(Kl + rb + ((kc * 16) ^ sw)) = k0;
            *(short8*)(Kl + rb + (((kc + 4) * 16) ^ sw)) = k1;

            const short8* vsrc = (const short8*)(qkv + base + (size_t)(kb + vkey) * 3072 + 2048 + h * 64);
            short8 v0 = vsrc[vc], v1 = vsrc[vc + 4];
            #pragma unroll
            for (int j = 0; j < 8; ++j) Vt[vc * 8 + j][vkey] = v0[j];
            #pragma unroll
            for (int j = 0; j < 8; ++j) Vt[(vc + 4) * 8 + j][vkey] = v1[j];
        }
        __syncthreads();

        f32x4 sacc[4];
        #pragma unroll
        for (int kt = 0; kt < 4; ++kt) { sacc[kt][0]=0.f; sacc[kt][1]=0.f; sacc[kt][2]=0.f; sacc[kt][3]=0.f; }
        #pragma unroll
        for (int ks = 0; ks < 2; ++ks) {
            short8 aq = ks ? aq1 : aq0;
            #pragma unroll
            for (int kt = 0; kt < 4; ++kt) {
                int krow = kt * 16 + lr;
                short8 bk = *(const short8*)(Kl + krow * 128 + (((ks * 4 + lg) * 16) ^ ((krow & 7) << 4)));
                sacc[kt] = __builtin_amdgcn_mfma_f32_16x16x32_bf16(aq, bk, sacc[kt], 0, 0, 0);
            }
        }

        #pragma unroll
        for (int kt = 0; kt < 4; ++kt) {
            int key = kb + kt * 16 + lr;
            #pragma unroll
            for (int j = 0; j < 4; ++j) {
                int q = qbase + w * 16 + lg * 4 + j;
                float pv = (key <= q) ? __expf(sacc[kt][j] * 0.125f) : 0.f;
                lsum[j] += pv;
                Ps[w * 16 + lg * 4 + j][kt * 16 + lr] = (short)f2bf(pv);
            }
        }

        #pragma unroll
        for (int ks = 0; ks < 2; ++ks) {
            short8 ap = *(const short8*)&Ps[w * 16 + lr][ks * 32 + lg * 8];
            #pragma unroll
            for (int dt = 0; dt < 4; ++dt) {
                short8 bv = *(const short8*)&Vt[dt * 16 + lr][ks * 32 + lg * 8];
                oacc[dt] = __builtin_amdgcn_mfma_f32_16x16x32_bf16(ap, bv, oacc[dt], 0, 0, 0);
            }
        }
        __syncthreads();
    }

    #pragma unroll
    for (int j = 0; j < 4; ++j) {
        float l = lsum[j];
        l += __shfl_xor(l, 1); l += __shfl_xor(l, 2);
        l += __shfl_xor(l, 4); l += __shfl_xor(l, 8);
        float inv = 1.f / l;
        int qrow = qbase + w * 16 + lg * 4 + j;
        __hip_bfloat16* dst = y + (size_t)(b * 1024 + qrow) * 1024 + h * 64;
        #pragma unroll
        for (int dt = 0; dt < 4; ++dt)
            dst[dt * 16 + lr] = __float2bfloat16(oacc[dt][j] * inv);
    }
}

// ---------------------------------------------------------------------------
// Host launch (r17/r18 layout).
// ---------------------------------------------------------------------------
extern "C" void kernel_launch(void* const* d_in, const int* in_sizes, int n_in,
                              void* d_out, int out_size, void* d_ws, size_t ws_size,
                              hipStream_t stream)
{
    (void)in_sizes; (void)n_in; (void)out_size; (void)ws_size;

    const int*   ids    = (const int*)d_in[0];
    const float* wte    = (const float*)d_in[1];
    const float* wpe    = (const float*)d_in[2];
    const float* ln1_g  = (const float*)d_in[3];
    const float* ln1_b  = (const float*)d_in[4];
    const float* w_qkv  = (const float*)d_in[5];
    const float* b_qkv  = (const float*)d_in[6];
    const float* w_proj = (const float*)d_in[7];
    const float* b_proj = (const float*)d_in[8];
    const float* ln2_g  = (const float*)d_in[9];
    const float* ln2_b  = (const float*)d_in[10];
    const float* w_fc1  = (const float*)d_in[11];
    const float* b_fc1  = (const float*)d_in[12];
    const float* w_fc2  = (const float*)d_in[13];
    const float* b_fc2  = (const float*)d_in[14];
    const float* lnf_g  = (const float*)d_in[15];
    const float* lnf_b  = (const float*)d_in[16];
    const float* w_lm   = (const float*)d_in[17];

    char* ws = (char*)d_ws;
    __hip_bfloat16* abuf_bf = (__hip_bfloat16*)ws;                    // 4 MB
    float*          hbuf    = (float*)(ws + (4u<<20));                // 8 MB
    __hip_bfloat16* qkvb_bf = (__hip_bfloat16*)(ws + (12u<<20));      // 12 MB
    __hip_bfloat16* ybuf_bf = (__hip_bfloat16*)(ws + (24u<<20));      // 4 MB
    __hip_bfloat16* mbuf_bf = (__hip_bfloat16*)(ws + (28u<<20));      // 16 MB
    __hip_bfloat16* wlm_bf  = (__hip_bfloat16*)(ws + (4u<<20));       // 65.5 MB (end)

    __hip_bfloat16* wq_bf = (__hip_bfloat16*)d_out;
    __hip_bfloat16* wp_bf = wq_bf + (size_t)4*1024*3072;
    __hip_bfloat16* w1_bf = wp_bf + (size_t)4*1024*1024;
    __hip_bfloat16* w2_bf = w1_bf + (size_t)4*1024*4096;

    float* out = (float*)d_out;   // f32 logits

    tc_kernel<<<dim3(16, 48, 4), 256, 0, stream>>>(w_qkv,  wq_bf, 3072, 1024);
    tc_kernel<<<dim3(16, 16, 4), 256, 0, stream>>>(w_proj, wp_bf, 1024, 1024);
    tc_kernel<<<dim3(16, 64, 4), 256, 0, stream>>>(w_fc1,  w1_bf, 4096, 1024);
    tc_kernel<<<dim3(64, 16, 4), 256, 0, stream>>>(w_fc2,  w2_bf, 1024, 4096);

    embed_kernel<<<2048, 256, 0, stream>>>(ids, wte, wpe, hbuf);

    for (int l = 0; l < 4; ++l) {
        ln_kernel<<<2048, 256, 0, stream>>>(hbuf, ln1_g + l*1024, ln1_b + l*1024, abuf_bf);
        gemm_bf16<true,false><<<dim3(16, 24), 256, 0, stream>>>(
            abuf_bf, wq_bf + (size_t)l*1024*3072, b_qkv + l*3072, nullptr, qkvb_bf, 2048, 3072, 1024);
        attn_mfma<<<512, 256, 0, stream>>>(qkvb_bf, ybuf_bf);
        gemm_bf16<false,false><<<dim3(16, 8), 256, 0, stream>>>(
            ybuf_bf, wp_bf + (size_t)l*1024*1024, b_proj + l*1024, hbuf, hbuf, 2048, 1024, 1024);
        ln_kernel<<<2048, 256, 0, stream>>>(hbuf, ln2_g + l*1024, ln2_b + l*1024, abuf_bf);
        gemm_bf16<true,true><<<dim3(16, 32), 256, 0, stream>>>(
            abuf_bf, w1_bf + (size_t)l*1024*4096, b_fc1 + l*4096, nullptr, mbuf_bf, 2048, 4096, 1024);
        gemm_bf16<false,false><<<dim3(16, 8), 256, 0, stream>>>(
            mbuf_bf, w2_bf + (size_t)l*4096*1024, b_fc2 + l*1024, hbuf, hbuf, 2048, 1024, 4096);
    }

    ln_kernel<<<2048, 256, 0, stream>>>(hbuf, lnf_g, lnf_b, abuf_bf);
    tc_kernel<<<dim3(16, 500, 1), 256, 0, stream>>>(w_lm, wlm_bf, 32000, 1024);
    gemm_bf16<false,false><<<dim3(16, 250), 256, 0, stream>>>(
        abuf_bf, wlm_bf, nullptr, nullptr, out, 2048, 32000, 1024);
}

// Round 20
// 1042.795 us; speedup vs baseline: 11.0471x; 1.1573x over previous
//
#include <hip/hip_runtime.h>
#include <hip/hip_bf16.h>
#include <math.h>

typedef __attribute__((ext_vector_type(4))) float f32x4;
typedef __attribute__((ext_vector_type(8))) short short8;
typedef __attribute__((ext_vector_type(4))) unsigned short ushort4v;

__device__ __forceinline__ unsigned short f2bf(float f) {
    return __builtin_bit_cast(unsigned short, __float2bfloat16(f));
}

__device__ __forceinline__ void gload16(const void* g, void* l) {
    __builtin_amdgcn_global_load_lds(
        (const __attribute__((address_space(1))) unsigned int*)g,
        (__attribute__((address_space(3))) unsigned int*)l, 16, 0, 0);
}

// ---------------------------------------------------------------------------
// Transpose-cast: in f32 [K][N] (layer z) -> out bf16 [N][K] (k-contiguous)
// ---------------------------------------------------------------------------
__global__ __launch_bounds__(256)
void tc_kernel(const float* __restrict__ in, __hip_bfloat16* __restrict__ out,
               int N, int K)
{
    __shared__ float tile[64][65];
    const size_t loff = (size_t)blockIdx.z * K * N;
    const int k0 = blockIdx.x * 64, n0 = blockIdx.y * 64;
    const int t = threadIdx.x;
    {
        int kk = t >> 2, nb = (t & 3) * 16;
        const float* src = in + loff + (size_t)(k0 + kk) * N + n0 + nb;
        #pragma unroll
        for (int j = 0; j < 4; ++j) {
            float4 v = *(const float4*)(src + j * 4);
            tile[kk][nb + j*4 + 0] = v.x; tile[kk][nb + j*4 + 1] = v.y;
            tile[kk][nb + j*4 + 2] = v.z; tile[kk][nb + j*4 + 3] = v.w;
        }
    }
    __syncthreads();
    {
        int nn = t >> 2, kb = (t & 3) * 16;
        __hip_bfloat16* dst = out + loff + (size_t)(n0 + nn) * K + k0 + kb;
        short8 w0, w1;
        #pragma unroll
        for (int j = 0; j < 8; ++j) w0[j] = (short)f2bf(tile[kb + j][nn]);
        #pragma unroll
        for (int j = 0; j < 8; ++j) w1[j] = (short)f2bf(tile[kb + 8 + j][nn]);
        *(short8*)dst = w0;
        *(short8*)(dst + 8) = w1;
    }
}

// ---------------------------------------------------------------------------
// Embedding (f32 out)
// ---------------------------------------------------------------------------
__global__ __launch_bounds__(256)
void embed_kernel(const int* __restrict__ ids, const float* __restrict__ wte,
                  const float* __restrict__ wpe, float* __restrict__ h)
{
    int row  = blockIdx.x;
    int tpos = row & 1023;
    int id   = ids[row];
    float4 a = ((const float4*)(wte + (size_t)id * 1024))[threadIdx.x];
    float4 p = ((const float4*)(wpe + (size_t)tpos * 1024))[threadIdx.x];
    float4 o; o.x = a.x + p.x; o.y = a.y + p.y; o.z = a.z + p.z; o.w = a.w + p.w;
    ((float4*)(h + (size_t)row * 1024))[threadIdx.x] = o;
}

// ---------------------------------------------------------------------------
// LayerNorm: f32 in, BF16 out
// ---------------------------------------------------------------------------
__global__ __launch_bounds__(256)
void ln_kernel(const float* __restrict__ x, const float* __restrict__ g,
               const float* __restrict__ b, __hip_bfloat16* __restrict__ out)
{
    size_t row = blockIdx.x;
    float4 v = ((const float4*)(x + row * 1024))[threadIdx.x];
    float s  = v.x + v.y + v.z + v.w;
    float s2 = v.x*v.x + v.y*v.y + v.z*v.z + v.w*v.w;
    #pragma unroll
    for (int off = 32; off; off >>= 1) {
        s  += __shfl_xor(s, off);
        s2 += __shfl_xor(s2, off);
    }
    __shared__ float rs[4], rs2[4];
    int wave = threadIdx.x >> 6;
    if ((threadIdx.x & 63) == 0) { rs[wave] = s; rs2[wave] = s2; }
    __syncthreads();
    s  = rs[0] + rs[1] + rs[2] + rs[3];
    s2 = rs2[0] + rs2[1] + rs2[2] + rs2[3];
    float mean = s * (1.f / 1024.f);
    float var  = s2 * (1.f / 1024.f) - mean * mean;
    float rstd = rsqrtf(var + 1e-5f);
    float4 gg = ((const float4*)g)[threadIdx.x];
    float4 bb = ((const float4*)b)[threadIdx.x];
    ushort4v ov;
    ov[0] = f2bf((v.x - mean) * rstd * gg.x + bb.x);
    ov[1] = f2bf((v.y - mean) * rstd * gg.y + bb.y);
    ov[2] = f2bf((v.z - mean) * rstd * gg.z + bb.z);
    ov[3] = f2bf((v.w - mean) * rstd * gg.w + bb.w);
    ((ushort4v*)(out + row * 1024))[threadIdx.x] = ov;
}

// ---------------------------------------------------------------------------
// All-bf16 GEMM, global_load_lds staging (r19 structure, proven).
// BN = 128 (4 waves x 64x64) or 64 (4 waves x 64x32, 2x grid for small N).
// NT: nontemporal C stores (LM head: keep w_lm L3-resident).
// ---------------------------------------------------------------------------
template<bool OUT_BF16, bool GELU_ACT, bool NT, int BN>
__global__ __launch_bounds__(256)
void gemm_bf16(const __hip_bfloat16* __restrict__ A,
               const __hip_bfloat16* __restrict__ Bt,
               const float* __restrict__ bias, const float* __restrict__ resid,
               void* __restrict__ Cout, int M, int N, int K)
{
    __shared__ unsigned char smem[16384 + BN * 128];
    const int m0 = blockIdx.x * 128;
    const int n0 = blockIdx.y * BN;
    const int t    = threadIdx.x;
    const int lane = t & 63;
    const int wave = t >> 6;
    constexpr int NF = (BN == 128) ? 4 : 2;   // n-frags per wave
    const int wm = (BN == 128) ? (wave >> 1) * 64 : (wave & 1) * 64;
    const int wn = (BN == 128) ? (wave & 1) * 64 : (wave >> 1) * 32;

    f32x4 acc[4][NF];
    #pragma unroll
    for (int i = 0; i < 4; ++i)
        #pragma unroll
        for (int j = 0; j < NF; ++j) {
            acc[i][j][0] = 0.f; acc[i][j][1] = 0.f; acc[i][j][2] = 0.f; acc[i][j][3] = 0.f;
        }

    // ---- staging addressing (hoisted) ----
    const int l8 = lane >> 3;
    const int lc = (lane & 7) ^ l8;
    constexpr int NB = NF;                    // B gloads per thread
    const __hip_bfloat16* agp[4];
    const __hip_bfloat16* bgp[NB];
    void* alds[4];
    void* blds[NB];
    #pragma unroll
    for (int i = 0; i < 4; ++i) {
        int row = wave * 32 + i * 8 + l8;
        agp[i] = A + (size_t)(m0 + row) * K + lc * 8;
        alds[i] = (void*)(smem + (wave * 32 + i * 8) * 128);
    }
    #pragma unroll
    for (int i = 0; i < NB; ++i) {
        int row = wave * (BN / 4) + i * 8 + l8;
        bgp[i] = Bt + (size_t)(n0 + row) * K + lc * 8;
        blds[i] = (void*)(smem + 16384 + (wave * (BN / 4) + i * 8) * 128);
    }

    for (int k0 = 0; k0 < K; k0 += 64) {
        #pragma unroll
        for (int i = 0; i < 4; ++i) gload16(agp[i] + k0, alds[i]);
        #pragma unroll
        for (int i = 0; i < NB; ++i) gload16(bgp[i] + k0, blds[i]);
        __syncthreads();
        const int lr = lane & 15;
        const int lk = lane >> 4;
        #pragma unroll
        for (int ks = 0; ks < 2; ++ks) {
            int chunk = ks * 4 + lk;
            short8 af[4], bfr[NF];
            #pragma unroll
            for (int m = 0; m < 4; ++m) {
                int row = wm + m * 16 + lr;
                af[m] = *(const short8*)(smem + row * 128 + ((chunk * 16) ^ ((row & 7) << 4)));
            }
            #pragma unroll
            for (int n = 0; n < NF; ++n) {
                int nn = wn + n * 16 + lr;
                bfr[n] = *(const short8*)(smem + 16384 + nn * 128 + ((chunk * 16) ^ ((nn & 7) << 4)));
            }
            #pragma unroll
            for (int m = 0; m < 4; ++m)
                #pragma unroll
                for (int n = 0; n < NF; ++n)
                    acc[m][n] = __builtin_amdgcn_mfma_f32_16x16x32_bf16(af[m], bfr[n], acc[m][n], 0, 0, 0);
        }
        __syncthreads();
    }

    const int lr = lane & 15;
    const int lq = lane >> 4;
    #pragma unroll
    for (int n = 0; n < NF; ++n) {
        int col = n0 + wn + n * 16 + lr;
        float bv = bias ? bias[col] : 0.f;
        #pragma unroll
        for (int m = 0; m < 4; ++m) {
            int rbase = m0 + wm + m * 16 + lq * 4;
            #pragma unroll
            for (int j = 0; j < 4; ++j) {
                int row = rbase + j;
                float v = acc[m][n][j] + bv;
                if (resid) v += resid[(size_t)row * N + col];
                if (GELU_ACT) v = 0.5f * v * (1.f + erff(v * 0.70710678118654752f));
                if (OUT_BF16) {
                    ((__hip_bfloat16*)Cout)[(size_t)row * N + col] = __float2bfloat16(v);
                } else if (NT) {
                    __builtin_nontemporal_store(v, (float*)Cout + (size_t)row * N + col);
                } else {
                    ((float*)Cout)[(size_t)row * N + col] = v;
                }
            }
        }
    }
}

// ---------------------------------------------------------------------------
// MFMA causal attention (r18, proven)
// ---------------------------------------------------------------------------
__global__ __launch_bounds__(256)
void attn_mfma(const __hip_bfloat16* __restrict__ qkv,
               __hip_bfloat16* __restrict__ y)
{
    __shared__ short Qs[64][72];
    __shared__ short Ps[64][72];
    __shared__ unsigned char Kl[8192];
    __shared__ short Vt[64][72];

    const int bid = blockIdx.x;
    const int p   = bid >> 5;
    const int qt  = (p < 8) ? (15 - 2 * p) : (2 * (p - 8));
    const int bh  = bid & 31;
    const int b = bh >> 4, h = bh & 15;
    const int t = threadIdx.x, lane = t & 63, w = t >> 6;
    const int lr = lane & 15, lg = lane >> 4;
    const size_t base = (size_t)b * 1024 * 3072;
    const int qbase = qt * 64;

    {
        int row = t >> 2, c = t & 3;
        const short8* qsrc = (const short8*)(qkv + base + (size_t)(qbase + row) * 3072 + h * 64);
        *(short8*)&Qs[row][c * 8]      = qsrc[c];
        *(short8*)&Qs[row][c * 8 + 32] = qsrc[c + 4];
    }
    __syncthreads();

    short8 aq0 = *(const short8*)&Qs[w * 16 + lr][0 * 32 + lg * 8];
    short8 aq1 = *(const short8*)&Qs[w * 16 + lr][1 * 32 + lg * 8];

    f32x4 oacc[4];
    #pragma unroll
    for (int dt = 0; dt < 4; ++dt) { oacc[dt][0]=0.f; oacc[dt][1]=0.f; oacc[dt][2]=0.f; oacc[dt][3]=0.f; }
    float lsum[4] = {0.f, 0.f, 0.f, 0.f};

    const int ntiles = qt + 1;
    const int kkey = t >> 2, kc = t & 3;
    const int vkey = t & 63, vc = t >> 6;

    for (int tile = 0; tile < ntiles; ++tile) {
        const int kb = tile * 64;
        {
            const short8* ksrc = (const short8*)(qkv + base + (size_t)(kb + kkey) * 3072 + 1024 + h * 64);
            short8 k0 = ksrc[kc], k1 = ksrc[kc + 4];
            int rb = kkey * 128, sw = (kkey & 7) << 4;
            *(short8*)(Kl + rb + ((kc * 16) ^ sw)) = k0;
            *(short8*)(Kl + rb + (((kc + 4) * 16) ^ sw)) = k1;

            const short8* vsrc = (const short8*)(qkv + base + (size_t)(kb + vkey) * 3072 + 2048 + h * 64);
            short8 v0 = vsrc[vc], v1 = vsrc[vc + 4];
            #pragma unroll
            for (int j = 0; j < 8; ++j) Vt[vc * 8 + j][vkey] = v0[j];
            #pragma unroll
            for (int j = 0; j < 8; ++j) Vt[(vc + 4) * 8 + j][vkey] = v1[j];
        }
        __syncthreads();

        f32x4 sacc[4];
        #pragma unroll
        for (int kt = 0; kt < 4; ++kt) { sacc[kt][0]=0.f; sacc[kt][1]=0.f; sacc[kt][2]=0.f; sacc[kt][3]=0.f; }
        #pragma unroll
        for (int ks = 0; ks < 2; ++ks) {
            short8 aq = ks ? aq1 : aq0;
            #pragma unroll
            for (int kt = 0; kt < 4; ++kt) {
                int krow = kt * 16 + lr;
                short8 bk = *(const short8*)(Kl + krow * 128 + (((ks * 4 + lg) * 16) ^ ((krow & 7) << 4)));
                sacc[kt] = __builtin_amdgcn_mfma_f32_16x16x32_bf16(aq, bk, sacc[kt], 0, 0, 0);
            }
        }

        #pragma unroll
        for (int kt = 0; kt < 4; ++kt) {
            int key = kb + kt * 16 + lr;
            #pragma unroll
            for (int j = 0; j < 4; ++j) {
                int q = qbase + w * 16 + lg * 4 + j;
                float pv = (key <= q) ? __expf(sacc[kt][j] * 0.125f) : 0.f;
                lsum[j] += pv;
                Ps[w * 16 + lg * 4 + j][kt * 16 + lr] = (short)f2bf(pv);
            }
        }

        #pragma unroll
        for (int ks = 0; ks < 2; ++ks) {
            short8 ap = *(const short8*)&Ps[w * 16 + lr][ks * 32 + lg * 8];
            #pragma unroll
            for (int dt = 0; dt < 4; ++dt) {
                short8 bv = *(const short8*)&Vt[dt * 16 + lr][ks * 32 + lg * 8];
                oacc[dt] = __builtin_amdgcn_mfma_f32_16x16x32_bf16(ap, bv, oacc[dt], 0, 0, 0);
            }
        }
        __syncthreads();
    }

    #pragma unroll
    for (int j = 0; j < 4; ++j) {
        float l = lsum[j];
        l += __shfl_xor(l, 1); l += __shfl_xor(l, 2);
        l += __shfl_xor(l, 4); l += __shfl_xor(l, 8);
        float inv = 1.f / l;
        int qrow = qbase + w * 16 + lg * 4 + j;
        __hip_bfloat16* dst = y + (size_t)(b * 1024 + qrow) * 1024 + h * 64;
        #pragma unroll
        for (int dt = 0; dt < 4; ++dt)
            dst[dt * 16 + lr] = __float2bfloat16(oacc[dt][j] * inv);
    }
}

// ---------------------------------------------------------------------------
// Host launch (r17/r18 layout).
// ---------------------------------------------------------------------------
extern "C" void kernel_launch(void* const* d_in, const int* in_sizes, int n_in,
                              void* d_out, int out_size, void* d_ws, size_t ws_size,
                              hipStream_t stream)
{
    (void)in_sizes; (void)n_in; (void)out_size; (void)ws_size;

    const int*   ids    = (const int*)d_in[0];
    const float* wte    = (const float*)d_in[1];
    const float* wpe    = (const float*)d_in[2];
    const float* ln1_g  = (const float*)d_in[3];
    const float* ln1_b  = (const float*)d_in[4];
    const float* w_qkv  = (const float*)d_in[5];
    const float* b_qkv  = (const float*)d_in[6];
    const float* w_proj = (const float*)d_in[7];
    const float* b_proj = (const float*)d_in[8];
    const float* ln2_g  = (const float*)d_in[9];
    const float* ln2_b  = (const float*)d_in[10];
    const float* w_fc1  = (const float*)d_in[11];
    const float* b_fc1  = (const float*)d_in[12];
    const float* w_fc2  = (const float*)d_in[13];
    const float* b_fc2  = (const float*)d_in[14];
    const float* lnf_g  = (const float*)d_in[15];
    const float* lnf_b  = (const float*)d_in[16];
    const float* w_lm   = (const float*)d_in[17];

    char* ws = (char*)d_ws;
    __hip_bfloat16* abuf_bf = (__hip_bfloat16*)ws;                    // 4 MB
    float*          hbuf    = (float*)(ws + (4u<<20));                // 8 MB
    __hip_bfloat16* qkvb_bf = (__hip_bfloat16*)(ws + (12u<<20));      // 12 MB
    __hip_bfloat16* ybuf_bf = (__hip_bfloat16*)(ws + (24u<<20));      // 4 MB
    __hip_bfloat16* mbuf_bf = (__hip_bfloat16*)(ws + (28u<<20));      // 16 MB
    __hip_bfloat16* wlm_bf  = (__hip_bfloat16*)(ws + (4u<<20));       // 65.5 MB (end)

    __hip_bfloat16* wq_bf = (__hip_bfloat16*)d_out;
    __hip_bfloat16* wp_bf = wq_bf + (size_t)4*1024*3072;
    __hip_bfloat16* w1_bf = wp_bf + (size_t)4*1024*1024;
    __hip_bfloat16* w2_bf = w1_bf + (size_t)4*1024*4096;

    float* out = (float*)d_out;   // f32 logits

    tc_kernel<<<dim3(16, 48, 4), 256, 0, stream>>>(w_qkv,  wq_bf, 3072, 1024);
    tc_kernel<<<dim3(16, 16, 4), 256, 0, stream>>>(w_proj, wp_bf, 1024, 1024);
    tc_kernel<<<dim3(16, 64, 4), 256, 0, stream>>>(w_fc1,  w1_bf, 4096, 1024);
    tc_kernel<<<dim3(64, 16, 4), 256, 0, stream>>>(w_fc2,  w2_bf, 1024, 4096);

    embed_kernel<<<2048, 256, 0, stream>>>(ids, wte, wpe, hbuf);

    for (int l = 0; l < 4; ++l) {
        ln_kernel<<<2048, 256, 0, stream>>>(hbuf, ln1_g + l*1024, ln1_b + l*1024, abuf_bf);
        gemm_bf16<true,false,false,128><<<dim3(16, 24), 256, 0, stream>>>(
            abuf_bf, wq_bf + (size_t)l*1024*3072, b_qkv + l*3072, nullptr, qkvb_bf, 2048, 3072, 1024);
        attn_mfma<<<512, 256, 0, stream>>>(qkvb_bf, ybuf_bf);
        gemm_bf16<false,false,false,64><<<dim3(16, 16), 256, 0, stream>>>(
            ybuf_bf, wp_bf + (size_t)l*1024*1024, b_proj + l*1024, hbuf, hbuf, 2048, 1024, 1024);
        ln_kernel<<<2048, 256, 0, stream>>>(hbuf, ln2_g + l*1024, ln2_b + l*1024, abuf_bf);
        gemm_bf16<true,true,false,128><<<dim3(16, 32), 256, 0, stream>>>(
            abuf_bf, w1_bf + (size_t)l*1024*4096, b_fc1 + l*4096, nullptr, mbuf_bf, 2048, 4096, 1024);
        gemm_bf16<false,false,false,64><<<dim3(16, 16), 256, 0, stream>>>(
            mbuf_bf, w2_bf + (size_t)l*4096*1024, b_fc2 + l*1024, hbuf, hbuf, 2048, 1024, 4096);
    }

    ln_kernel<<<2048, 256, 0, stream>>>(hbuf, lnf_g, lnf_b, abuf_bf);
    tc_kernel<<<dim3(16, 500, 1), 256, 0, stream>>>(w_lm, wlm_bf, 32000, 1024);
    gemm_bf16<false,false,true,128><<<dim3(16, 250), 256, 0, stream>>>(
        abuf_bf, wlm_bf, nullptr, nullptr, out, 2048, 32000, 1024);
}